// Round 1
// baseline (263350.757 us; speedup 1.0000x reference)
//
#include <hip/hip_runtime.h>
#include <hip/hip_cooperative_groups.h>
#include <math.h>

namespace cg = cooperative_groups;

#define N 2048
#define DIMS 784
#define BIGV 1.0e6f
#define NC 784

// two-sided block Jacobi config: 128 teams of width 16, 32x32 local tiles
#define NB 128
#define NPAIRS 64
#define NSWEEPS 18
#define NTRI 2016      // 64*63/2 upper-tri pair tiles
#define NVS  2048      // 64 pairs * 32 V row-stripes

// round-robin pairing over nteams: round r in [0,nteams-1), pair m in [0,nteams/2)
__device__ __forceinline__ void rr_pairN(int r, int m, int nteams, int& bi, int& bj) {
    int n1 = nteams - 1;
    if (m == 0) { bi = n1; bj = r % n1; }
    else { bi = (r + m) % n1; bj = (r - m + n1) % n1; }
}

// ---------------- distances ----------------
__global__ void k_rowsq(const float* __restrict__ X, float* __restrict__ sq) {
    int wave = threadIdx.x >> 6, lane = threadIdx.x & 63;
    int row = blockIdx.x * 4 + wave;
    const float* xr = X + (size_t)row * DIMS;
    float s = 0.f;
    for (int k = lane; k < DIMS; k += 64) { float v = xr[k]; s += v * v; }
    for (int off = 32; off; off >>= 1) s += __shfl_down(s, off);
    if (lane == 0) sq[row] = s;
}

__global__ void __launch_bounds__(256) k_dist(const float* __restrict__ X,
                                              const float* __restrict__ sq,
                                              float* __restrict__ out) {
    __shared__ float As[64][17], Bs[64][17];
    int ti = blockIdx.y, tj = blockIdx.x, t = threadIdx.x;
    int tx = t & 15, ty = t >> 4;
    float acc[4][4] = {};
    for (int k0 = 0; k0 < DIMS; k0 += 16) {
        for (int e = 0; e < 4; e++) {
            int idx = t + e * 256; int r = idx >> 4, c = idx & 15;
            As[r][c] = X[(size_t)(ti * 64 + r) * DIMS + k0 + c];
            Bs[r][c] = X[(size_t)(tj * 64 + r) * DIMS + k0 + c];
        }
        __syncthreads();
        for (int k = 0; k < 16; k++) {
            float a[4], b[4];
            for (int e = 0; e < 4; e++) a[e] = As[ty * 4 + e][k];
            for (int f = 0; f < 4; f++) b[f] = Bs[tx * 4 + f][k];
            for (int e = 0; e < 4; e++)
                for (int f = 0; f < 4; f++) acc[e][f] += a[e] * b[f];
        }
        __syncthreads();
    }
    for (int e = 0; e < 4; e++)
        for (int f = 0; f < 4; f++) {
            int gi = ti * 64 + ty * 4 + e, gj = tj * 64 + tx * 4 + f;
            float d2 = sq[gi] + sq[gj] - 2.f * acc[e][f];
            out[(size_t)gi * N + gj] = sqrtf(fmaxf(d2, 0.f));
        }
}

// ---------------- KNN graph ----------------
__global__ void k_knn(const float* __restrict__ dist, float* __restrict__ G) {
    int i = blockIdx.x, t = threadIdx.x;
    float bv[6]; int bidx[6];
    for (int k = 0; k < 6; k++) { bv[k] = 3.4e38f; bidx[k] = N; }
    const float* dr = dist + (size_t)i * N;
    for (int j = t; j < N; j += 256) {
        float v = dr[j];
        bool ins = (v < bv[5]) || (v == bv[5] && j < bidx[5]);
        if (ins) {
            int k = 5;
            while (k > 0) {
                bool mv = (v < bv[k - 1]) || (v == bv[k - 1] && j < bidx[k - 1]);
                if (!mv) break;
                bv[k] = bv[k - 1]; bidx[k] = bidx[k - 1]; k--;
            }
            bv[k] = v; bidx[k] = j;
        }
    }
    __shared__ float lv[256][6]; __shared__ int li[256][6];
    for (int k = 0; k < 6; k++) { lv[t][k] = bv[k]; li[t][k] = bidx[k]; }
    __syncthreads();
    for (int off = 128; off >= 1; off >>= 1) {
        if (t < off) {
            float av[6], cv[6]; int ai[6], ci[6];
            for (int k = 0; k < 6; k++) { av[k] = lv[t][k]; ai[k] = li[t][k]; cv[k] = lv[t + off][k]; ci[k] = li[t + off][k]; }
            float mv[6]; int mi[6]; int pa = 0, pb = 0;
            for (int k = 0; k < 6; k++) {
                bool ta;
                if (pa >= 6) ta = false;
                else if (pb >= 6) ta = true;
                else ta = (av[pa] < cv[pb]) || (av[pa] == cv[pb] && ai[pa] < ci[pb]);
                if (ta) { mv[k] = av[pa]; mi[k] = ai[pa]; pa++; }
                else    { mv[k] = cv[pb]; mi[k] = ci[pb]; pb++; }
            }
            for (int k = 0; k < 6; k++) { lv[t][k] = mv[k]; li[t][k] = mi[k]; }
        }
        __syncthreads();
    }
    float sv[6]; int si[6];
    for (int k = 0; k < 6; k++) { sv[k] = lv[0][k]; si[k] = li[0][k]; }
    for (int j = t; j < N; j += 256) {
        float val = BIGV;
        for (int k = 0; k < 6; k++) if (j == si[k]) val = sv[k];
        G[(size_t)i * N + j] = val;
    }
}

__global__ void k_symdiag(float* __restrict__ G) {
    int idx = blockIdx.x * 256 + threadIdx.x;
    int i = idx >> 11, j = idx & 2047;
    if (i == j) { G[idx] = 0.f; return; }
    if (j > i) {
        float a = G[(size_t)i * N + j], b = G[(size_t)j * N + i];
        float m = fminf(a, b);
        G[(size_t)i * N + j] = m; G[(size_t)j * N + i] = m;
    }
}

// ---------------- blocked Floyd-Warshall ----------------
__global__ void __launch_bounds__(256) k_fw12(float* __restrict__ D, int kb) {
    __shared__ float KK[64][65], C[64][65];
    int bx = blockIdx.x, t = threadIdx.x;
    for (int e = 0; e < 16; e++) { int idx = t + e * 256; int r = idx >> 6, c = idx & 63;
        KK[r][c] = D[(size_t)(kb * 64 + r) * N + kb * 64 + c]; }
    __syncthreads();
    int r0 = t >> 2, c0 = (t & 3) * 16;
    for (int k = 0; k < 64; k++) {
        float dk = KK[r0][k];
        for (int c = 0; c < 16; c++) KK[r0][c0 + c] = fminf(KK[r0][c0 + c], dk + KK[k][c0 + c]);
        __syncthreads();
    }
    if (bx == 62) {
        for (int e = 0; e < 16; e++) { int idx = t + e * 256; int r = idx >> 6, c = idx & 63;
            D[(size_t)(kb * 64 + r) * N + kb * 64 + c] = KK[r][c]; }
        return;
    }
    bool rowstripe = bx < 31;
    int o = rowstripe ? bx : bx - 31;
    o += (o >= kb) ? 1 : 0;
    int baseR = rowstripe ? kb : o;
    int baseC = rowstripe ? o : kb;
    for (int e = 0; e < 16; e++) { int idx = t + e * 256; int r = idx >> 6, c = idx & 63;
        C[r][c] = D[(size_t)(baseR * 64 + r) * N + baseC * 64 + c]; }
    __syncthreads();
    if (rowstripe) {
        for (int k = 0; k < 64; k++) {
            float dk = KK[r0][k];
            for (int c = 0; c < 16; c++) C[r0][c0 + c] = fminf(C[r0][c0 + c], dk + C[k][c0 + c]);
            __syncthreads();
        }
    } else {
        for (int k = 0; k < 64; k++) {
            float dk = C[r0][k];
            for (int c = 0; c < 16; c++) C[r0][c0 + c] = fminf(C[r0][c0 + c], dk + KK[k][c0 + c]);
            __syncthreads();
        }
    }
    for (int e = 0; e < 16; e++) { int idx = t + e * 256; int r = idx >> 6, c = idx & 63;
        D[(size_t)(baseR * 64 + r) * N + baseC * 64 + c] = C[r][c]; }
}

__global__ void __launch_bounds__(256) k_fw3(float* __restrict__ D, int kb) {
    int bi = blockIdx.y, bj = blockIdx.x;
    if (bi == kb || bj == kb) return;
    __shared__ float R[64][65], Cl[64][65];
    int t = threadIdx.x;
    for (int e = 0; e < 16; e++) { int idx = t + e * 256; int r = idx >> 6, c = idx & 63;
        R[r][c]  = D[(size_t)(bi * 64 + r) * N + kb * 64 + c];
        Cl[r][c] = D[(size_t)(kb * 64 + r) * N + bj * 64 + c]; }
    __syncthreads();
    int r0 = (t >> 4) * 4, c0 = (t & 15) * 4;
    float acc[4][4];
    for (int e = 0; e < 4; e++) for (int f = 0; f < 4; f++) acc[e][f] = 3.4e38f;
    for (int k = 0; k < 64; k++) {
        float a[4], b[4];
        for (int e = 0; e < 4; e++) a[e] = R[r0 + e][k];
        for (int f = 0; f < 4; f++) b[f] = Cl[k][c0 + f];
        for (int e = 0; e < 4; e++)
            for (int f = 0; f < 4; f++) acc[e][f] = fminf(acc[e][f], a[e] + b[f]);
    }
    for (int e = 0; e < 4; e++)
        for (int f = 0; f < 4; f++) {
            size_t off = (size_t)(bi * 64 + r0 + e) * N + bj * 64 + c0 + f;
            D[off] = fminf(D[off], acc[e][f]);
        }
}

// ---------------- double centering ----------------
__global__ void k_rowmean(const float* __restrict__ D, double* __restrict__ rm) {
    int i = blockIdx.x, t = threadIdx.x;
    const float* dr = D + (size_t)i * N;
    double s = 0;
    for (int j = t; j < N; j += 256) { double d = (double)dr[j]; s += d * d; }
    __shared__ double red[256];
    red[t] = s; __syncthreads();
    for (int off = 128; off; off >>= 1) { if (t < off) red[t] += red[t + off]; __syncthreads(); }
    if (t == 0) rm[i] = red[0] / (double)N;
}

__global__ void k_grand(const double* __restrict__ rm, double* __restrict__ gm) {
    int t = threadIdx.x;
    double s = 0;
    for (int i = t; i < N; i += 256) s += rm[i];
    __shared__ double red[256];
    red[t] = s; __syncthreads();
    for (int off = 128; off; off >>= 1) { if (t < off) red[t] += red[t + off]; __syncthreads(); }
    if (t == 0) gm[0] = red[0] / (double)N;
}

__global__ void k_buildB(const float* __restrict__ D, const double* __restrict__ rm,
                         const double* __restrict__ gm, double* __restrict__ A) {
    int idx = blockIdx.x * 256 + threadIdx.x;
    int i = idx >> 11, j = idx & 2047;
    double d = (double)D[idx];
    A[idx] = -0.5 * (d * d - rm[i] - rm[j] + gm[0]);
}

__global__ void k_setV(float* __restrict__ V) {
    int idx = blockIdx.x * 256 + threadIdx.x;
    int i = idx >> 11, j = idx & 2047;
    V[idx] = (i == j) ? 1.f : 0.f;
}

// ---------------- Jacobi control ----------------
__global__ void k_initflags(unsigned* flags) { flags[0] = 0u; flags[1] = 0u; flags[2] = 0u; }
// legacy fallback only
__global__ void k_sweepctl(unsigned* flags) {
    if (!flags[2]) {
        float mo = __uint_as_float(flags[0]), md = __uint_as_float(flags[1]);
        if (md > 0.f && mo <= 2e-9f * md) { flags[2] = 1u; return; }
        flags[0] = 0u; flags[1] = 0u;
    }
}

// =====================================================================
// Fused cooperative Jacobi: whole sweep loop in ONE kernel.
// Per round: phase1 = local diag (blocks 0..63) || V-apply of previous
// round (remaining blocks, double-buffered qb/qfl by round parity);
// grid.sync; phase2 = tri-apply (all blocks); grid.sync.
// Convergence evaluated at sweep boundary -> exact early break.
// =====================================================================
__global__ void __launch_bounds__(256, 4) k_jacobi(double* __restrict__ A, float* __restrict__ V,
                                                   double* __restrict__ qb, int* __restrict__ qfl,
                                                   unsigned* __restrict__ flags) {
    cg::grid_group grid = cg::this_grid();
    const int t = threadIdx.x;
    const int blk = blockIdx.x;
    const int G = (int)gridDim.x;

    // 16896B union buffer: local {M,Q} / tri {T,Qb} / vapply {Qs,Tv}
    __shared__ double shbuf[2112];
    __shared__ double cA[16], sA[16];
    __shared__ int ppA[16], qqA[16];
    __shared__ float red1[256], red2[256];
    __shared__ int everr;
    __shared__ unsigned s_done;

    double (*M)[33]  = (double(*)[33])shbuf;          // 32x33 fp64
    double (*Q)[33]  = (double(*)[33])(shbuf + 1056); // 32x33 fp64
    double (*T)[33]  = M;                             // tri aliases
    double (*Qb)[33] = Q;
    float (*Qs)[33]  = (float(*)[33])shbuf;           // 32x33 f32
    float (*Tv)[33]  = (float(*)[33])(shbuf + 1056);  // 64x33 f32 (8448B exact)

    // ---- V <- V*Q for one 64-row stripe ----
    auto do_v = [&](int task, int rnd, const double* qbP, const int* qflP) {
        int p = task >> 5, rt = task & 31;
        if (!qflP[p]) return;
        int bi, bj; rr_pairN(rnd, p, NB, bi, bj);
        for (int e = 0; e < 4; e++) {
            int idx = t + e * 256; int a = idx >> 5, c = idx & 31;
            Qs[a][c] = (float)qbP[(size_t)p * 1024 + idx];
        }
        for (int e = 0; e < 8; e++) {
            int idx = t + e * 256; int a = idx >> 5, c = idx & 31;
            int gc = (c < 16) ? bi * 16 + c : bj * 16 + (c - 16);
            Tv[a][c] = V[(size_t)(rt * 64 + a) * N + gc];
        }
        __syncthreads();
        int r0 = (t >> 4) * 4, c0 = (t & 15) * 2;
        float acc[4][2] = {};
        for (int y = 0; y < 32; y++) {
            float q0 = Qs[y][c0], q1 = Qs[y][c0 + 1];
            for (int e = 0; e < 4; e++) {
                float vv = Tv[r0 + e][y];
                acc[e][0] += vv * q0; acc[e][1] += vv * q1;
            }
        }
        for (int e = 0; e < 4; e++)
            for (int f = 0; f < 2; f++) {
                int x = c0 + f;
                int gc = (x < 16) ? bi * 16 + x : bj * 16 + (x - 16);
                V[(size_t)(rt * 64 + r0 + e) * N + gc] = acc[e][f];
            }
        __syncthreads();   // protect shared reuse across task-loop iterations
    };

    // ---- A <- Qr^T A Qc on upper-tri pair tile (writes tile + mirror) ----
    auto do_tri = [&](int task, int rnd, const double* qbC, const int* qflC) {
        int pr = 0, rem = task;
        while (rem >= 63 - pr) { rem -= 63 - pr; pr++; }
        int pc = pr + 1 + rem;
        int fr = qflC[pr], fc = qflC[pc];
        if (!fr && !fc) return;
        int bir, bjr, bic, bjc;
        rr_pairN(rnd, pr, NB, bir, bjr);
        rr_pairN(rnd, pc, NB, bic, bjc);
        for (int e = 0; e < 4; e++) {
            int idx = t + e * 256; int a = idx >> 5, c = idx & 31;
            if (fr) Qb[a][c] = qbC[(size_t)pr * 1024 + idx];
            int gr = (a < 16) ? bir * 16 + a : bjr * 16 + (a - 16);
            int gc = (c < 16) ? bic * 16 + c : bjc * 16 + (c - 16);
            T[a][c] = A[(size_t)gr * N + gc];
        }
        __syncthreads();
        int x0 = (t >> 4) * 2, c0 = (t & 15) * 2;
        if (fr) {
            double a00 = 0, a01 = 0, a10 = 0, a11 = 0;
            for (int y = 0; y < 32; y++) {
                double q0 = Qb[y][x0], q1 = Qb[y][x0 + 1];
                double v0 = T[y][c0], v1 = T[y][c0 + 1];
                a00 += q0 * v0; a01 += q0 * v1;
                a10 += q1 * v0; a11 += q1 * v1;
            }
            __syncthreads();
            T[x0][c0] = a00; T[x0][c0 + 1] = a01;
            T[x0 + 1][c0] = a10; T[x0 + 1][c0 + 1] = a11;
            __syncthreads();
        }
        if (fc) {
            for (int e = 0; e < 4; e++) {
                int idx = t + e * 256; int a = idx >> 5, c = idx & 31;
                Qb[a][c] = qbC[(size_t)pc * 1024 + idx];
            }
            __syncthreads();
            double a00 = 0, a01 = 0, a10 = 0, a11 = 0;
            for (int y = 0; y < 32; y++) {
                double v0 = T[x0][y], v1 = T[x0 + 1][y];
                double q0 = Qb[y][c0], q1 = Qb[y][c0 + 1];
                a00 += v0 * q0; a01 += v0 * q1;
                a10 += v1 * q0; a11 += v1 * q1;
            }
            __syncthreads();
            T[x0][c0] = a00; T[x0][c0 + 1] = a01;
            T[x0 + 1][c0] = a10; T[x0 + 1][c0 + 1] = a11;
            __syncthreads();
        }
        for (int e = 0; e < 4; e++) {
            int idx = t + e * 256; int a = idx >> 5, c = idx & 31;
            int gr = (a < 16) ? bir * 16 + a : bjr * 16 + (a - 16);
            int gc = (c < 16) ? bic * 16 + c : bjc * 16 + (c - 16);
            A[(size_t)gr * N + gc] = T[a][c];
            int gr2 = (a < 16) ? bic * 16 + a : bjc * 16 + (a - 16);
            int gc2 = (c < 16) ? bir * 16 + c : bjr * 16 + (c - 16);
            A[(size_t)gr2 * N + gc2] = T[c][a];
        }
        __syncthreads();   // protect shared reuse across task-loop iterations
    };

    int pendRound = -1, pendPar = 0;
    int g = 0;
    for (int sw = 0; sw < NSWEEPS; sw++) {
        for (int r = 0; r < NB - 1; r++, g++) {
            const int par = g & 1;
            double* qbC = qb + (size_t)par * (NPAIRS * 1024);
            int* qflC = qfl + par * NPAIRS;

            // ---------- phase 1: local diag (blocks 0..63) || pending V ----------
            if (blk < NPAIRS) {
                int p = blk;
                int bi, bj; rr_pairN(r, p, NB, bi, bj);
                float offm = 0.f, diagm = 0.f;
                for (int e = 0; e < 4; e++) {
                    int idx = t + e * 256; int x = idx >> 5, y = idx & 31;
                    int gr = (x < 16) ? bi * 16 + x : bj * 16 + (x - 16);
                    int gc = (y < 16) ? bi * 16 + y : bj * 16 + (y - 16);
                    double v = A[(size_t)gr * N + gc];
                    M[x][y] = v;
                    float av = (float)fabs(v);
                    if (x == y) diagm = fmaxf(diagm, av); else offm = fmaxf(offm, av);
                    Q[x][y] = (x == y) ? 1.0 : 0.0;
                }
                red1[t] = offm; red2[t] = diagm;
                if (t == 0) everr = 0;
                __syncthreads();
                for (int off = 128; off; off >>= 1) {
                    if (t < off) { red1[t] = fmaxf(red1[t], red1[t + off]); red2[t] = fmaxf(red2[t], red2[t + off]); }
                    __syncthreads();
                }
                float dmaxf = red2[0], off0 = red1[0];
                if (t == 0) { atomicMax(flags + 0, __float_as_uint(off0)); atomicMax(flags + 1, __float_as_uint(dmaxf)); }
                double dmax = (double)dmaxf;
                if ((double)off0 <= 1e-9 * dmax) {
                    if (t == 0) qflC[p] = 0;
                } else {
                    double thr = fmax(1e-13 * dmax, 1e-5 * (double)off0);
                    for (int ir = 0; ir < 31; ir++) {
                        if (t < 16) {
                            int pp, qq; rr_pairN(ir, t, 32, pp, qq);
                            double app = M[pp][pp], aqq = M[qq][qq], apq = M[pp][qq];
                            double c = 1.0, sn = 0.0;
                            if (fabs(apq) > thr) {
                                double tau = (aqq - app) / (2.0 * apq);
                                double tt2 = ((tau >= 0.0) ? 1.0 : -1.0) / (fabs(tau) + sqrt(1.0 + tau * tau));
                                c = 1.0 / sqrt(1.0 + tt2 * tt2);
                                sn = tt2 * c;
                                everr = 1;
                            }
                            ppA[t] = pp; qqA[t] = qq; cA[t] = c; sA[t] = sn;
                        }
                        __syncthreads();
                        for (int e = 0; e < 2; e++) {
                            int slot = t + e * 256; int mm = slot >> 5, k = slot & 31;
                            double sn = sA[mm];
                            if (sn != 0.0) {
                                int pp = ppA[mm], qq = qqA[mm]; double c = cA[mm];
                                double a0 = M[k][pp], b0 = M[k][qq];
                                M[k][pp] = c * a0 - sn * b0; M[k][qq] = sn * a0 + c * b0;
                                a0 = Q[k][pp]; b0 = Q[k][qq];
                                Q[k][pp] = c * a0 - sn * b0; Q[k][qq] = sn * a0 + c * b0;
                            }
                        }
                        __syncthreads();
                        for (int e = 0; e < 2; e++) {
                            int slot = t + e * 256; int mm = slot >> 5, k = slot & 31;
                            double sn = sA[mm];
                            if (sn != 0.0) {
                                int pp = ppA[mm], qq = qqA[mm]; double c = cA[mm];
                                double a0 = M[pp][k], b0 = M[qq][k];
                                M[pp][k] = c * a0 - sn * b0; M[qq][k] = sn * a0 + c * b0;
                            }
                        }
                        __syncthreads();
                    }
                    int ev = everr;
                    if (t == 0) qflC[p] = ev;
                    if (ev) {
                        for (int e = 0; e < 4; e++) {
                            int idx = t + e * 256; int x = idx >> 5, y = idx & 31;
                            qbC[(size_t)p * 1024 + idx] = Q[x][y];
                            int gr = (x < 16) ? bi * 16 + x : bj * 16 + (x - 16);
                            int gc = (y < 16) ? bi * 16 + y : bj * 16 + (y - 16);
                            A[(size_t)gr * N + gc] = M[x][y];
                        }
                    }
                }
            } else if (pendRound >= 0) {
                const double* qbP = qb + (size_t)pendPar * (NPAIRS * 1024);
                const int* qflP = qfl + pendPar * NPAIRS;
                for (int task = blk - NPAIRS; task < NVS; task += G - NPAIRS)
                    do_v(task, pendRound, qbP, qflP);
            }
            grid.sync();

            // ---------- phase 2: tri-apply ----------
            for (int task = blk; task < NTRI; task += G)
                do_tri(task, r, qbC, qflC);
            pendRound = r; pendPar = par;
            grid.sync();
        }
        // ---------- sweep boundary: convergence check ----------
        if (blk == 0 && t == 0) {
            float mo = __uint_as_float(flags[0]), md = __uint_as_float(flags[1]);
            if (md > 0.f && mo <= 2e-9f * md) flags[2] = 1u;
            else { flags[0] = 0u; flags[1] = 0u; }
        }
        grid.sync();
        if (t == 0) s_done = *(volatile unsigned*)(flags + 2);
        __syncthreads();
        if (s_done) break;
    }
    // drain pending V-apply of the last executed round
    if (pendRound >= 0) {
        const double* qbP = qb + (size_t)pendPar * (NPAIRS * 1024);
        const int* qflP = qfl + pendPar * NPAIRS;
        for (int task = blk; task < NVS; task += G)
            do_v(task, pendRound, qbP, qflP);
    }
}

// ---------------- legacy fallback kernels (used only if coop launch fails) ----------------
__global__ void __launch_bounds__(256) k_local(double* __restrict__ A, double* __restrict__ qb,
                                               int* __restrict__ qfl, unsigned* __restrict__ flags,
                                               int round) {
    int p = blockIdx.x, t = threadIdx.x;
    if (flags[2]) { if (t == 0) qfl[p] = 0; return; }
    __shared__ double M[32][33], Q[32][33];
    __shared__ double cA[16], sA[16];
    __shared__ int ppA[16], qqA[16];
    __shared__ float red1[256], red2[256];
    __shared__ int everr;
    int bi, bj; rr_pairN(round, p, NB, bi, bj);

    float offm = 0.f, diagm = 0.f;
    for (int e = 0; e < 4; e++) {
        int idx = t + e * 256; int x = idx >> 5, y = idx & 31;
        int gr = (x < 16) ? bi * 16 + x : bj * 16 + (x - 16);
        int gc = (y < 16) ? bi * 16 + y : bj * 16 + (y - 16);
        double v = A[(size_t)gr * N + gc];
        M[x][y] = v;
        float av = (float)fabs(v);
        if (x == y) diagm = fmaxf(diagm, av); else offm = fmaxf(offm, av);
        Q[x][y] = (x == y) ? 1.0 : 0.0;
    }
    red1[t] = offm; red2[t] = diagm;
    if (t == 0) everr = 0;
    __syncthreads();
    for (int off = 128; off; off >>= 1) {
        if (t < off) { red1[t] = fmaxf(red1[t], red1[t + off]); red2[t] = fmaxf(red2[t], red2[t + off]); }
        __syncthreads();
    }
    float dmaxf = red2[0], off0 = red1[0];
    if (t == 0) { atomicMax(flags + 0, __float_as_uint(off0)); atomicMax(flags + 1, __float_as_uint(dmaxf)); }
    double dmax = (double)dmaxf;
    if ((double)off0 <= 1e-9 * dmax) { if (t == 0) qfl[p] = 0; return; }
    double thr = fmax(1e-13 * dmax, 1e-5 * (double)off0);

    for (int ir = 0; ir < 31; ir++) {
        if (t < 16) {
            int pp, qq; rr_pairN(ir, t, 32, pp, qq);
            double app = M[pp][pp], aqq = M[qq][qq], apq = M[pp][qq];
            double c = 1.0, sn = 0.0;
            if (fabs(apq) > thr) {
                double tau = (aqq - app) / (2.0 * apq);
                double tt2 = ((tau >= 0.0) ? 1.0 : -1.0) / (fabs(tau) + sqrt(1.0 + tau * tau));
                c = 1.0 / sqrt(1.0 + tt2 * tt2);
                sn = tt2 * c;
                everr = 1;
            }
            ppA[t] = pp; qqA[t] = qq; cA[t] = c; sA[t] = sn;
        }
        __syncthreads();
        for (int e = 0; e < 2; e++) {
            int slot = t + e * 256; int mm = slot >> 5, k = slot & 31;
            double sn = sA[mm];
            if (sn != 0.0) {
                int pp = ppA[mm], qq = qqA[mm]; double c = cA[mm];
                double a = M[k][pp], b = M[k][qq];
                M[k][pp] = c * a - sn * b; M[k][qq] = sn * a + c * b;
                a = Q[k][pp]; b = Q[k][qq];
                Q[k][pp] = c * a - sn * b; Q[k][qq] = sn * a + c * b;
            }
        }
        __syncthreads();
        for (int e = 0; e < 2; e++) {
            int slot = t + e * 256; int mm = slot >> 5, k = slot & 31;
            double sn = sA[mm];
            if (sn != 0.0) {
                int pp = ppA[mm], qq = qqA[mm]; double c = cA[mm];
                double a = M[pp][k], b = M[qq][k];
                M[pp][k] = c * a - sn * b; M[qq][k] = sn * a + c * b;
            }
        }
        __syncthreads();
    }
    int ev = everr;
    if (t == 0) qfl[p] = ev;
    if (ev) {
        for (int e = 0; e < 4; e++) {
            int idx = t + e * 256; int x = idx >> 5, y = idx & 31;
            qb[(size_t)p * 1024 + idx] = Q[x][y];
            int gr = (x < 16) ? bi * 16 + x : bj * 16 + (x - 16);
            int gc = (y < 16) ? bi * 16 + y : bj * 16 + (y - 16);
            A[(size_t)gr * N + gc] = M[x][y];
        }
    }
}

__global__ void __launch_bounds__(256) k_apply(double* __restrict__ A, float* __restrict__ V,
                                               const double* __restrict__ qb,
                                               const int* __restrict__ qfl,
                                               const unsigned* __restrict__ flags, int round) {
    if (flags[2]) return;
    int t = threadIdx.x;
    int task = blockIdx.x;
    if (task < NTRI) {
        int pr = 0, rem = task;
        while (rem >= 63 - pr) { rem -= 63 - pr; pr++; }
        int pc = pr + 1 + rem;
        int fr = qfl[pr], fc = qfl[pc];
        if (!fr && !fc) return;
        __shared__ double T[32][33], Qb[32][33];
        int bir, bjr, bic, bjc;
        rr_pairN(round, pr, NB, bir, bjr);
        rr_pairN(round, pc, NB, bic, bjc);
        for (int e = 0; e < 4; e++) {
            int idx = t + e * 256; int a = idx >> 5, b = idx & 31;
            if (fr) Qb[a][b] = qb[(size_t)pr * 1024 + idx];
            int gr = (a < 16) ? bir * 16 + a : bjr * 16 + (a - 16);
            int gc = (b < 16) ? bic * 16 + b : bjc * 16 + (b - 16);
            T[a][b] = A[(size_t)gr * N + gc];
        }
        __syncthreads();
        int x0 = (t >> 4) * 2, c0 = (t & 15) * 2;
        if (fr) {
            double acc[2][2] = {};
            for (int y = 0; y < 32; y++) {
                double q0 = Qb[y][x0], q1 = Qb[y][x0 + 1];
                double v0 = T[y][c0], v1 = T[y][c0 + 1];
                acc[0][0] += q0 * v0; acc[0][1] += q0 * v1;
                acc[1][0] += q1 * v0; acc[1][1] += q1 * v1;
            }
            __syncthreads();
            T[x0][c0] = acc[0][0]; T[x0][c0 + 1] = acc[0][1];
            T[x0 + 1][c0] = acc[1][0]; T[x0 + 1][c0 + 1] = acc[1][1];
            __syncthreads();
        }
        if (fc) {
            for (int e = 0; e < 4; e++) {
                int idx = t + e * 256; int a = idx >> 5, b = idx & 31;
                Qb[a][b] = qb[(size_t)pc * 1024 + idx];
            }
            __syncthreads();
            double acc[2][2] = {};
            for (int y = 0; y < 32; y++) {
                double v0 = T[x0][y], v1 = T[x0 + 1][y];
                double q0 = Qb[y][c0], q1 = Qb[y][c0 + 1];
                acc[0][0] += v0 * q0; acc[0][1] += v0 * q1;
                acc[1][0] += v1 * q0; acc[1][1] += v1 * q1;
            }
            __syncthreads();
            T[x0][c0] = acc[0][0]; T[x0][c0 + 1] = acc[0][1];
            T[x0 + 1][c0] = acc[1][0]; T[x0 + 1][c0 + 1] = acc[1][1];
            __syncthreads();
        }
        for (int e = 0; e < 4; e++) {
            int idx = t + e * 256; int a = idx >> 5, b = idx & 31;
            int gr = (a < 16) ? bir * 16 + a : bjr * 16 + (a - 16);
            int gc = (b < 16) ? bic * 16 + b : bjc * 16 + (b - 16);
            A[(size_t)gr * N + gc] = T[a][b];
            int gr2 = (a < 16) ? bic * 16 + a : bjc * 16 + (a - 16);
            int gc2 = (b < 16) ? bir * 16 + b : bjr * 16 + (b - 16);
            A[(size_t)gr2 * N + gc2] = T[b][a];
        }
    } else {
        int v = task - NTRI; int p = v >> 5, rt = v & 31;
        if (!qfl[p]) return;
        __shared__ float Qs[32][33], Tv[64][33];
        int bi, bj; rr_pairN(round, p, NB, bi, bj);
        for (int e = 0; e < 4; e++) {
            int idx = t + e * 256; int a = idx >> 5, b = idx & 31;
            Qs[a][b] = (float)qb[(size_t)p * 1024 + idx];
        }
        for (int e = 0; e < 8; e++) {
            int idx = t + e * 256; int a = idx >> 5, b = idx & 31;
            int gc = (b < 16) ? bi * 16 + b : bj * 16 + (b - 16);
            Tv[a][b] = V[(size_t)(rt * 64 + a) * N + gc];
        }
        __syncthreads();
        int r0 = (t >> 4) * 4, c0 = (t & 15) * 2;
        float acc[4][2] = {};
        for (int y = 0; y < 32; y++) {
            float q0 = Qs[y][c0], q1 = Qs[y][c0 + 1];
            for (int e = 0; e < 4; e++) {
                float vv = Tv[r0 + e][y];
                acc[e][0] += vv * q0; acc[e][1] += vv * q1;
            }
        }
        for (int e = 0; e < 4; e++)
            for (int f = 0; f < 2; f++) {
                int x = c0 + f;
                int gc = (x < 16) ? bi * 16 + x : bj * 16 + (x - 16);
                V[(size_t)(rt * 64 + r0 + e) * N + gc] = acc[e][f];
            }
    }
}

// ---------------- epilogue ----------------
__global__ void k_lambda(const double* __restrict__ A, double* __restrict__ lam) {
    int i = blockIdx.x * 256 + threadIdx.x;
    if (i < N) lam[i] = A[(size_t)i * N + i];
}

__global__ void __launch_bounds__(1024) k_sort(const double* __restrict__ lam,
                                               double* __restrict__ lams, int* __restrict__ order) {
    __shared__ double v[2048]; __shared__ int ix[2048];
    int t = threadIdx.x;
    v[t] = lam[t]; v[t + 1024] = lam[t + 1024];
    ix[t] = t; ix[t + 1024] = t + 1024;
    __syncthreads();
    for (int k = 2; k <= 2048; k <<= 1) {
        for (int j = k >> 1; j > 0; j >>= 1) {
            int l = ((t & ~(j - 1)) << 1) | (t & (j - 1));
            int partner = l | j;
            double va = v[l], vb = v[partner]; int ia = ix[l], ib = ix[partner];
            bool before = (va > vb) || (va == vb && ia < ib);
            bool asc = ((l & k) == 0);
            bool doSwap = asc ? (!before) : before;
            if (doSwap) { v[l] = vb; v[partner] = va; ix[l] = ib; ix[partner] = ia; }
            __syncthreads();
        }
    }
    lams[t] = v[t]; lams[t + 1024] = v[t + 1024];
    order[t] = ix[t]; order[t + 1024] = ix[t + 1024];
}

__global__ void k_out(const float* __restrict__ Vm, const double* __restrict__ lams,
                      const int* __restrict__ order, float* __restrict__ out) {
    int c = blockIdx.x, t = threadIdx.x;
    int col = order[c];
    __shared__ float rv[256]; __shared__ int ri[256];
    float bv = -1.f; int bidx = N;
    for (int i = t; i < N; i += 256) {
        float av = fabsf(Vm[(size_t)i * N + col]);
        if (av > bv || (av == bv && i < bidx)) { bv = av; bidx = i; }
    }
    rv[t] = bv; ri[t] = bidx;
    __syncthreads();
    for (int off = 128; off; off >>= 1) {
        if (t < off) {
            if (rv[t + off] > rv[t] || (rv[t + off] == rv[t] && ri[t + off] < ri[t])) {
                rv[t] = rv[t + off]; ri[t] = ri[t + off];
            }
        }
        __syncthreads();
    }
    float sv = Vm[(size_t)ri[0] * N + col];
    float s = (sv > 0.f) ? 1.f : ((sv < 0.f) ? -1.f : 0.f);
    double lv = lams[c];
    float f = s * (float)sqrt(lv > 0.0 ? lv : 0.0);
    for (int i = t; i < N; i += 256) out[(size_t)i * NC + c] = Vm[(size_t)i * N + col] * f;
}

extern "C" void kernel_launch(void* const* d_in, const int* in_sizes, int n_in,
                              void* d_out, int out_size, void* d_ws, size_t ws_size,
                              hipStream_t stream) {
    (void)in_sizes; (void)n_in; (void)out_size; (void)ws_size;
    const float* X = (const float*)d_in[0];
    float* out = (float*)d_out;

    double* rm  = (double*)d_ws;                 // N
    double* gm  = rm + N;                        // 1 (+7 pad)
    double* lam = gm + 8;                        // N
    double* lams= lam + N;                       // N
    double* A   = lams + N;                      // N*N fp64
    double* qb  = A + (size_t)N * N;             // 2 * NPAIRS*1024 fp64 (double-buffered)
    float* Dg   = (float*)(qb + 2 * (size_t)NPAIRS * 1024); // N*N f32
    float* Vm   = Dg + (size_t)N * N;            // N*N f32
    float* sq   = Vm + (size_t)N * N;            // N
    int* order  = (int*)(sq + N);                // N
    int* qfl    = order + N;                     // 2 * NPAIRS
    unsigned* flags = (unsigned*)(qfl + 2 * NPAIRS); // 3
    float* dist = (float*)A;                     // alias: dist dies before A is born

    // 1. pairwise distances
    k_rowsq<<<N / 4, 256, 0, stream>>>(X, sq);
    k_dist<<<dim3(32, 32), 256, 0, stream>>>(X, sq, dist);

    // 2. KNN graph
    k_knn<<<N, 256, 0, stream>>>(dist, Dg);
    k_symdiag<<<(N * N) / 256, 256, 0, stream>>>(Dg);

    // 3. blocked Floyd-Warshall
    for (int kb = 0; kb < N / 64; kb++) {
        k_fw12<<<63, 256, 0, stream>>>(Dg, kb);
        k_fw3<<<dim3(32, 32), 256, 0, stream>>>(Dg, kb);
    }

    // 4. double centering -> B (fp64)
    k_rowmean<<<N, 256, 0, stream>>>(Dg, rm);
    k_grand<<<1, 256, 0, stream>>>(rm, gm);
    k_buildB<<<(N * N) / 256, 256, 0, stream>>>(Dg, rm, gm, A);
    k_setV<<<(N * N) / 256, 256, 0, stream>>>(Vm);
    k_initflags<<<1, 1, 0, stream>>>(flags);

    // 5. two-sided block Jacobi — single cooperative kernel
    static int coopBlocks = -1;
    if (coopBlocks < 0) {
        int perCU = 0;
        if (hipOccupancyMaxActiveBlocksPerMultiprocessor(&perCU,
                reinterpret_cast<const void*>(k_jacobi), 256, 0) != hipSuccess || perCU < 1)
            perCU = 1;
        int ncu = 256;
        hipDeviceProp_t prop{};
        int dev = 0;
        if (hipGetDevice(&dev) == hipSuccess &&
            hipGetDeviceProperties(&prop, dev) == hipSuccess &&
            prop.multiProcessorCount > 0)
            ncu = prop.multiProcessorCount;
        long total = (long)perCU * (long)ncu;
        if (total > 1024) total = 1024;   // cap: 2016 tri tasks -> 2/block; keeps grid.sync cheap
        if (total < 256) total = 256;     // 1 block/CU always co-resident
        coopBlocks = (int)total;
    }
    {
        double* Aarg = A; float* Varg = Vm; double* qbArg = qb; int* qflArg = qfl; unsigned* flArg = flags;
        void* args[5] = { (void*)&Aarg, (void*)&Varg, (void*)&qbArg, (void*)&qflArg, (void*)&flArg };
        hipError_t err = hipLaunchCooperativeKernel(reinterpret_cast<const void*>(k_jacobi),
                                                    dim3(coopBlocks), dim3(256), args, 0, stream);
        if (err != hipSuccess) {
            // fallback: legacy multi-launch path (uses first qb/qfl buffer only)
            (void)hipGetLastError();
            for (int sw = 0; sw < NSWEEPS; sw++) {
                k_sweepctl<<<1, 1, 0, stream>>>(flags);
                for (int r = 0; r < NB - 1; r++) {
                    k_local<<<NPAIRS, 256, 0, stream>>>(A, qb, qfl, flags, r);
                    k_apply<<<NTRI + NVS, 256, 0, stream>>>(A, Vm, qb, qfl, flags, r);
                }
            }
        }
    }

    // 6. sort eigenvalues, sign-fix, scale, write output
    k_lambda<<<N / 256, 256, 0, stream>>>(A, lam);
    k_sort<<<1, 1024, 0, stream>>>(lam, lams, order);
    k_out<<<NC, 256, 0, stream>>>(Vm, lams, order, out);
}

// Round 3
// 94684.766 us; speedup vs baseline: 2.7813x; 2.7813x over previous
//
#include <hip/hip_runtime.h>
#include <math.h>

#define N 2048
#define DIMS 784
#define BIGV 1.0e6f
#define NC 784

// two-sided block Jacobi config: 128 teams of width 16, 32x32 local tiles
#define NB 128
#define NPAIRS 64
#define NSWEEPS 18
#define NTRI 2016      // 64*63/2 upper-tri pair tiles
#define NVS  2048      // 64 pairs * 32 V row-stripes

// round-robin pairing over nteams: round r in [0,nteams-1), pair m in [0,nteams/2)
__device__ __forceinline__ void rr_pairN(int r, int m, int nteams, int& bi, int& bj) {
    int n1 = nteams - 1;
    if (m == 0) { bi = n1; bj = r % n1; }
    else { bi = (r + m) % n1; bj = (r - m + n1) % n1; }
}

// ---------------- distances ----------------
__global__ void k_rowsq(const float* __restrict__ X, float* __restrict__ sq) {
    int wave = threadIdx.x >> 6, lane = threadIdx.x & 63;
    int row = blockIdx.x * 4 + wave;
    const float* xr = X + (size_t)row * DIMS;
    float s = 0.f;
    for (int k = lane; k < DIMS; k += 64) { float v = xr[k]; s += v * v; }
    for (int off = 32; off; off >>= 1) s += __shfl_down(s, off);
    if (lane == 0) sq[row] = s;
}

__global__ void __launch_bounds__(256) k_dist(const float* __restrict__ X,
                                              const float* __restrict__ sq,
                                              float* __restrict__ out) {
    __shared__ float As[64][17], Bs[64][17];
    int ti = blockIdx.y, tj = blockIdx.x, t = threadIdx.x;
    int tx = t & 15, ty = t >> 4;
    float acc[4][4] = {};
    for (int k0 = 0; k0 < DIMS; k0 += 16) {
        for (int e = 0; e < 4; e++) {
            int idx = t + e * 256; int r = idx >> 4, c = idx & 15;
            As[r][c] = X[(size_t)(ti * 64 + r) * DIMS + k0 + c];
            Bs[r][c] = X[(size_t)(tj * 64 + r) * DIMS + k0 + c];
        }
        __syncthreads();
        for (int k = 0; k < 16; k++) {
            float a[4], b[4];
            for (int e = 0; e < 4; e++) a[e] = As[ty * 4 + e][k];
            for (int f = 0; f < 4; f++) b[f] = Bs[tx * 4 + f][k];
            for (int e = 0; e < 4; e++)
                for (int f = 0; f < 4; f++) acc[e][f] += a[e] * b[f];
        }
        __syncthreads();
    }
    for (int e = 0; e < 4; e++)
        for (int f = 0; f < 4; f++) {
            int gi = ti * 64 + ty * 4 + e, gj = tj * 64 + tx * 4 + f;
            float d2 = sq[gi] + sq[gj] - 2.f * acc[e][f];
            out[(size_t)gi * N + gj] = sqrtf(fmaxf(d2, 0.f));
        }
}

// ---------------- KNN graph ----------------
__global__ void k_knn(const float* __restrict__ dist, float* __restrict__ G) {
    int i = blockIdx.x, t = threadIdx.x;
    float bv[6]; int bidx[6];
    for (int k = 0; k < 6; k++) { bv[k] = 3.4e38f; bidx[k] = N; }
    const float* dr = dist + (size_t)i * N;
    for (int j = t; j < N; j += 256) {
        float v = dr[j];
        bool ins = (v < bv[5]) || (v == bv[5] && j < bidx[5]);
        if (ins) {
            int k = 5;
            while (k > 0) {
                bool mv = (v < bv[k - 1]) || (v == bv[k - 1] && j < bidx[k - 1]);
                if (!mv) break;
                bv[k] = bv[k - 1]; bidx[k] = bidx[k - 1]; k--;
            }
            bv[k] = v; bidx[k] = j;
        }
    }
    __shared__ float lv[256][6]; __shared__ int li[256][6];
    for (int k = 0; k < 6; k++) { lv[t][k] = bv[k]; li[t][k] = bidx[k]; }
    __syncthreads();
    for (int off = 128; off >= 1; off >>= 1) {
        if (t < off) {
            float av[6], cv[6]; int ai[6], ci[6];
            for (int k = 0; k < 6; k++) { av[k] = lv[t][k]; ai[k] = li[t][k]; cv[k] = lv[t + off][k]; ci[k] = li[t + off][k]; }
            float mv[6]; int mi[6]; int pa = 0, pb = 0;
            for (int k = 0; k < 6; k++) {
                bool ta;
                if (pa >= 6) ta = false;
                else if (pb >= 6) ta = true;
                else ta = (av[pa] < cv[pb]) || (av[pa] == cv[pb] && ai[pa] < ci[pb]);
                if (ta) { mv[k] = av[pa]; mi[k] = ai[pa]; pa++; }
                else    { mv[k] = cv[pb]; mi[k] = ci[pb]; pb++; }
            }
            for (int k = 0; k < 6; k++) { lv[t][k] = mv[k]; li[t][k] = mi[k]; }
        }
        __syncthreads();
    }
    float sv[6]; int si[6];
    for (int k = 0; k < 6; k++) { sv[k] = lv[0][k]; si[k] = li[0][k]; }
    for (int j = t; j < N; j += 256) {
        float val = BIGV;
        for (int k = 0; k < 6; k++) if (j == si[k]) val = sv[k];
        G[(size_t)i * N + j] = val;
    }
}

__global__ void k_symdiag(float* __restrict__ G) {
    int idx = blockIdx.x * 256 + threadIdx.x;
    int i = idx >> 11, j = idx & 2047;
    if (i == j) { G[idx] = 0.f; return; }
    if (j > i) {
        float a = G[(size_t)i * N + j], b = G[(size_t)j * N + i];
        float m = fminf(a, b);
        G[(size_t)i * N + j] = m; G[(size_t)j * N + i] = m;
    }
}

// ---------------- blocked Floyd-Warshall ----------------
__global__ void __launch_bounds__(256) k_fw12(float* __restrict__ D, int kb) {
    __shared__ float KK[64][65], C[64][65];
    int bx = blockIdx.x, t = threadIdx.x;
    for (int e = 0; e < 16; e++) { int idx = t + e * 256; int r = idx >> 6, c = idx & 63;
        KK[r][c] = D[(size_t)(kb * 64 + r) * N + kb * 64 + c]; }
    __syncthreads();
    int r0 = t >> 2, c0 = (t & 3) * 16;
    for (int k = 0; k < 64; k++) {
        float dk = KK[r0][k];
        for (int c = 0; c < 16; c++) KK[r0][c0 + c] = fminf(KK[r0][c0 + c], dk + KK[k][c0 + c]);
        __syncthreads();
    }
    if (bx == 62) {
        for (int e = 0; e < 16; e++) { int idx = t + e * 256; int r = idx >> 6, c = idx & 63;
            D[(size_t)(kb * 64 + r) * N + kb * 64 + c] = KK[r][c]; }
        return;
    }
    bool rowstripe = bx < 31;
    int o = rowstripe ? bx : bx - 31;
    o += (o >= kb) ? 1 : 0;
    int baseR = rowstripe ? kb : o;
    int baseC = rowstripe ? o : kb;
    for (int e = 0; e < 16; e++) { int idx = t + e * 256; int r = idx >> 6, c = idx & 63;
        C[r][c] = D[(size_t)(baseR * 64 + r) * N + baseC * 64 + c]; }
    __syncthreads();
    if (rowstripe) {
        for (int k = 0; k < 64; k++) {
            float dk = KK[r0][k];
            for (int c = 0; c < 16; c++) C[r0][c0 + c] = fminf(C[r0][c0 + c], dk + C[k][c0 + c]);
            __syncthreads();
        }
    } else {
        for (int k = 0; k < 64; k++) {
            float dk = C[r0][k];
            for (int c = 0; c < 16; c++) C[r0][c0 + c] = fminf(C[r0][c0 + c], dk + KK[k][c0 + c]);
            __syncthreads();
        }
    }
    for (int e = 0; e < 16; e++) { int idx = t + e * 256; int r = idx >> 6, c = idx & 63;
        D[(size_t)(baseR * 64 + r) * N + baseC * 64 + c] = C[r][c]; }
}

__global__ void __launch_bounds__(256) k_fw3(float* __restrict__ D, int kb) {
    int bi = blockIdx.y, bj = blockIdx.x;
    if (bi == kb || bj == kb) return;
    __shared__ float R[64][65], Cl[64][65];
    int t = threadIdx.x;
    for (int e = 0; e < 16; e++) { int idx = t + e * 256; int r = idx >> 6, c = idx & 63;
        R[r][c]  = D[(size_t)(bi * 64 + r) * N + kb * 64 + c];
        Cl[r][c] = D[(size_t)(kb * 64 + r) * N + bj * 64 + c]; }
    __syncthreads();
    int r0 = (t >> 4) * 4, c0 = (t & 15) * 4;
    float acc[4][4];
    for (int e = 0; e < 4; e++) for (int f = 0; f < 4; f++) acc[e][f] = 3.4e38f;
    for (int k = 0; k < 64; k++) {
        float a[4], b[4];
        for (int e = 0; e < 4; e++) a[e] = R[r0 + e][k];
        for (int f = 0; f < 4; f++) b[f] = Cl[k][c0 + f];
        for (int e = 0; e < 4; e++)
            for (int f = 0; f < 4; f++) acc[e][f] = fminf(acc[e][f], a[e] + b[f]);
    }
    for (int e = 0; e < 4; e++)
        for (int f = 0; f < 4; f++) {
            size_t off = (size_t)(bi * 64 + r0 + e) * N + bj * 64 + c0 + f;
            D[off] = fminf(D[off], acc[e][f]);
        }
}

// ---------------- double centering ----------------
__global__ void k_rowmean(const float* __restrict__ D, double* __restrict__ rm) {
    int i = blockIdx.x, t = threadIdx.x;
    const float* dr = D + (size_t)i * N;
    double s = 0;
    for (int j = t; j < N; j += 256) { double d = (double)dr[j]; s += d * d; }
    __shared__ double red[256];
    red[t] = s; __syncthreads();
    for (int off = 128; off; off >>= 1) { if (t < off) red[t] += red[t + off]; __syncthreads(); }
    if (t == 0) rm[i] = red[0] / (double)N;
}

__global__ void k_grand(const double* __restrict__ rm, double* __restrict__ gm) {
    int t = threadIdx.x;
    double s = 0;
    for (int i = t; i < N; i += 256) s += rm[i];
    __shared__ double red[256];
    red[t] = s; __syncthreads();
    for (int off = 128; off; off >>= 1) { if (t < off) red[t] += red[t + off]; __syncthreads(); }
    if (t == 0) gm[0] = red[0] / (double)N;
}

__global__ void k_buildB(const float* __restrict__ D, const double* __restrict__ rm,
                         const double* __restrict__ gm, double* __restrict__ A) {
    int idx = blockIdx.x * 256 + threadIdx.x;
    int i = idx >> 11, j = idx & 2047;
    double d = (double)D[idx];
    A[idx] = -0.5 * (d * d - rm[i] - rm[j] + gm[0]);
}

__global__ void k_setV(float* __restrict__ V) {
    int idx = blockIdx.x * 256 + threadIdx.x;
    int i = idx >> 11, j = idx & 2047;
    V[idx] = (i == j) ? 1.f : 0.f;
}

// ---------------- Jacobi control ----------------
__global__ void k_initflags(unsigned* flags) { flags[0] = 0u; flags[1] = 0u; flags[2] = 0u; }
// once per sweep: convergence check on previous sweep's accumulated maxima, then reset
__global__ void k_sweepctl(unsigned* flags) {
    if (!flags[2]) {
        float mo = __uint_as_float(flags[0]), md = __uint_as_float(flags[1]);
        if (md > 0.f && mo <= 2e-9f * md) { flags[2] = 1u; return; }
        flags[0] = 0u; flags[1] = 0u;
    }
}

// ---- V <- V*Q for one 64-row stripe; shared by k_localv / k_vdrain ----
__device__ __forceinline__ void vapply_task(float* __restrict__ V, const double* __restrict__ qbP,
                                            const int* __restrict__ qp, int rnd, int task, int t) {
    int p = task >> 5, rt = task & 31;
    if (!qp[p]) return;
    __shared__ float Qs[32][33], Tv[64][33];
    int bi, bj; rr_pairN(rnd, p, NB, bi, bj);
    for (int e = 0; e < 4; e++) {
        int idx = t + e * 256; int a = idx >> 5, c = idx & 31;
        Qs[a][c] = (float)qbP[(size_t)p * 1024 + idx];
    }
    for (int e = 0; e < 8; e++) {
        int idx = t + e * 256; int a = idx >> 5, c = idx & 31;
        int gc = (c < 16) ? bi * 16 + c : bj * 16 + (c - 16);
        Tv[a][c] = V[(size_t)(rt * 64 + a) * N + gc];
    }
    __syncthreads();
    int r0 = (t >> 4) * 4, c0 = (t & 15) * 2;
    float acc[4][2] = {};
    for (int y = 0; y < 32; y++) {
        float q0 = Qs[y][c0], q1 = Qs[y][c0 + 1];
        for (int e = 0; e < 4; e++) {
            float vv = Tv[r0 + e][y];
            acc[e][0] += vv * q0; acc[e][1] += vv * q1;
        }
    }
    for (int e = 0; e < 4; e++)
        for (int f = 0; f < 2; f++) {
            int x = c0 + f;
            int gc = (x < 16) ? bi * 16 + x : bj * 16 + (x - 16);
            V[(size_t)(rt * 64 + r0 + e) * N + gc] = acc[e][f];
        }
}

// ---------------- local 32x32 Jacobi (blocks 0..63) || V-apply of pending round ----------------
// No inter-role dependency: local(r) touches A + qb/qfl[par]; V-apply(r-1) touches V + qb/qfl[pendP].
__global__ void __launch_bounds__(256) k_localv(double* __restrict__ A, float* __restrict__ V,
                                                double* __restrict__ qb,
                                                int* __restrict__ qfl, unsigned* __restrict__ flags,
                                                int round, int par, int pendR, int pendP) {
    int t = threadIdx.x;
    if (blockIdx.x >= NPAIRS) {
        if (pendR < 0) return;
        vapply_task(V, qb + (size_t)pendP * (NPAIRS * 1024), qfl + pendP * NPAIRS,
                    pendR, (int)blockIdx.x - NPAIRS, t);
        return;
    }
    int p = blockIdx.x;
    double* qbC = qb + (size_t)par * (NPAIRS * 1024);
    int* qflC = qfl + par * NPAIRS;
    if (flags[2]) { if (t == 0) qflC[p] = 0; return; }
    __shared__ double M[32][33], Q[32][33];
    __shared__ double cA[16], sA[16];
    __shared__ int ppA[16], qqA[16];
    __shared__ float red1[256], red2[256];
    __shared__ int everr;
    int bi, bj; rr_pairN(round, p, NB, bi, bj);

    float offm = 0.f, diagm = 0.f;
    for (int e = 0; e < 4; e++) {
        int idx = t + e * 256; int x = idx >> 5, y = idx & 31;
        int gr = (x < 16) ? bi * 16 + x : bj * 16 + (x - 16);
        int gc = (y < 16) ? bi * 16 + y : bj * 16 + (y - 16);
        double v = A[(size_t)gr * N + gc];
        M[x][y] = v;
        float av = (float)fabs(v);
        if (x == y) diagm = fmaxf(diagm, av); else offm = fmaxf(offm, av);
        Q[x][y] = (x == y) ? 1.0 : 0.0;
    }
    red1[t] = offm; red2[t] = diagm;
    if (t == 0) everr = 0;
    __syncthreads();
    for (int off = 128; off; off >>= 1) {
        if (t < off) { red1[t] = fmaxf(red1[t], red1[t + off]); red2[t] = fmaxf(red2[t], red2[t + off]); }
        __syncthreads();
    }
    float dmaxf = red2[0], off0 = red1[0];
    if (t == 0) { atomicMax(flags + 0, __float_as_uint(off0)); atomicMax(flags + 1, __float_as_uint(dmaxf)); }
    double dmax = (double)dmaxf;
    if ((double)off0 <= 1e-9 * dmax) { if (t == 0) qflC[p] = 0; return; }
    double thr = fmax(1e-13 * dmax, 1e-5 * (double)off0);

    for (int ir = 0; ir < 31; ir++) {
        if (t < 16) {
            int pp, qq; rr_pairN(ir, t, 32, pp, qq);
            double app = M[pp][pp], aqq = M[qq][qq], apq = M[pp][qq];
            double c = 1.0, sn = 0.0;
            if (fabs(apq) > thr) {
                double tau = (aqq - app) / (2.0 * apq);
                double tt2 = ((tau >= 0.0) ? 1.0 : -1.0) / (fabs(tau) + sqrt(1.0 + tau * tau));
                c = 1.0 / sqrt(1.0 + tt2 * tt2);
                sn = tt2 * c;
                everr = 1;
            }
            ppA[t] = pp; qqA[t] = qq; cA[t] = c; sA[t] = sn;
        }
        __syncthreads();
        // col updates: M <- M*J, Q <- Q*J  (512 slots, 2/thread)
        for (int e = 0; e < 2; e++) {
            int slot = t + e * 256; int mm = slot >> 5, k = slot & 31;
            double sn = sA[mm];
            if (sn != 0.0) {
                int pp = ppA[mm], qq = qqA[mm]; double c = cA[mm];
                double a = M[k][pp], b = M[k][qq];
                M[k][pp] = c * a - sn * b; M[k][qq] = sn * a + c * b;
                a = Q[k][pp]; b = Q[k][qq];
                Q[k][pp] = c * a - sn * b; Q[k][qq] = sn * a + c * b;
            }
        }
        __syncthreads();
        // row updates: M <- J^T * M
        for (int e = 0; e < 2; e++) {
            int slot = t + e * 256; int mm = slot >> 5, k = slot & 31;
            double sn = sA[mm];
            if (sn != 0.0) {
                int pp = ppA[mm], qq = qqA[mm]; double c = cA[mm];
                double a = M[pp][k], b = M[qq][k];
                M[pp][k] = c * a - sn * b; M[qq][k] = sn * a + c * b;
            }
        }
        __syncthreads();
    }
    int ev = everr;
    if (t == 0) qflC[p] = ev;
    if (ev) {
        for (int e = 0; e < 4; e++) {
            int idx = t + e * 256; int x = idx >> 5, y = idx & 31;
            qbC[(size_t)p * 1024 + idx] = Q[x][y];
            int gr = (x < 16) ? bi * 16 + x : bj * 16 + (x - 16);
            int gc = (y < 16) ? bi * 16 + y : bj * 16 + (y - 16);
            A[(size_t)gr * N + gc] = M[x][y];
        }
    }
}

// ---------------- tri-apply: A <- Qr^T A Qc on upper-tri pair tiles ----------------
__global__ void __launch_bounds__(256) k_tri(double* __restrict__ A,
                                             const double* __restrict__ qb,
                                             const int* __restrict__ qfl,
                                             const unsigned* __restrict__ flags,
                                             int round, int par) {
    if (flags[2]) return;
    const double* qbC = qb + (size_t)par * (NPAIRS * 1024);
    const int* qflC = qfl + par * NPAIRS;
    int t = threadIdx.x;
    int task = blockIdx.x;
    int pr = 0, rem = task;
    while (rem >= 63 - pr) { rem -= 63 - pr; pr++; }
    int pc = pr + 1 + rem;
    int fr = qflC[pr], fc = qflC[pc];
    if (!fr && !fc) return;
    __shared__ double T[32][33], Qb[32][33];
    int bir, bjr, bic, bjc;
    rr_pairN(round, pr, NB, bir, bjr);
    rr_pairN(round, pc, NB, bic, bjc);
    for (int e = 0; e < 4; e++) {
        int idx = t + e * 256; int a = idx >> 5, b = idx & 31;
        if (fr) Qb[a][b] = qbC[(size_t)pr * 1024 + idx];
        int gr = (a < 16) ? bir * 16 + a : bjr * 16 + (a - 16);
        int gc = (b < 16) ? bic * 16 + b : bjc * 16 + (b - 16);
        T[a][b] = A[(size_t)gr * N + gc];
    }
    __syncthreads();
    int x0 = (t >> 4) * 2, c0 = (t & 15) * 2;
    if (fr) {
        double a00 = 0, a01 = 0, a10 = 0, a11 = 0;
        for (int y = 0; y < 32; y++) {
            double q0 = Qb[y][x0], q1 = Qb[y][x0 + 1];
            double v0 = T[y][c0], v1 = T[y][c0 + 1];
            a00 += q0 * v0; a01 += q0 * v1;
            a10 += q1 * v0; a11 += q1 * v1;
        }
        __syncthreads();
        T[x0][c0] = a00; T[x0][c0 + 1] = a01;
        T[x0 + 1][c0] = a10; T[x0 + 1][c0 + 1] = a11;
        __syncthreads();
    }
    if (fc) {
        for (int e = 0; e < 4; e++) {
            int idx = t + e * 256; int a = idx >> 5, b = idx & 31;
            Qb[a][b] = qbC[(size_t)pc * 1024 + idx];
        }
        __syncthreads();
        double a00 = 0, a01 = 0, a10 = 0, a11 = 0;
        for (int y = 0; y < 32; y++) {
            double v0 = T[x0][y], v1 = T[x0 + 1][y];
            double q0 = Qb[y][c0], q1 = Qb[y][c0 + 1];
            a00 += v0 * q0; a01 += v0 * q1;
            a10 += v1 * q0; a11 += v1 * q1;
        }
        __syncthreads();
        T[x0][c0] = a00; T[x0][c0 + 1] = a01;
        T[x0 + 1][c0] = a10; T[x0 + 1][c0 + 1] = a11;
        __syncthreads();
    }
    for (int e = 0; e < 4; e++) {
        int idx = t + e * 256; int a = idx >> 5, b = idx & 31;
        int gr = (a < 16) ? bir * 16 + a : bjr * 16 + (a - 16);
        int gc = (b < 16) ? bic * 16 + b : bjc * 16 + (b - 16);
        A[(size_t)gr * N + gc] = T[a][b];
        int gr2 = (a < 16) ? bic * 16 + a : bjc * 16 + (a - 16);
        int gc2 = (b < 16) ? bir * 16 + b : bjr * 16 + (b - 16);
        A[(size_t)gr2 * N + gc2] = T[b][a];
    }
}

// drain: V-apply of the final round
__global__ void __launch_bounds__(256) k_vdrain(float* __restrict__ V, const double* __restrict__ qb,
                                                const int* __restrict__ qfl, int rnd, int par) {
    vapply_task(V, qb + (size_t)par * (NPAIRS * 1024), qfl + par * NPAIRS,
                rnd, (int)blockIdx.x, threadIdx.x);
}

// ---------------- epilogue ----------------
__global__ void k_lambda(const double* __restrict__ A, double* __restrict__ lam) {
    int i = blockIdx.x * 256 + threadIdx.x;
    if (i < N) lam[i] = A[(size_t)i * N + i];
}

__global__ void __launch_bounds__(1024) k_sort(const double* __restrict__ lam,
                                               double* __restrict__ lams, int* __restrict__ order) {
    __shared__ double v[2048]; __shared__ int ix[2048];
    int t = threadIdx.x;
    v[t] = lam[t]; v[t + 1024] = lam[t + 1024];
    ix[t] = t; ix[t + 1024] = t + 1024;
    __syncthreads();
    for (int k = 2; k <= 2048; k <<= 1) {
        for (int j = k >> 1; j > 0; j >>= 1) {
            int l = ((t & ~(j - 1)) << 1) | (t & (j - 1));
            int partner = l | j;
            double va = v[l], vb = v[partner]; int ia = ix[l], ib = ix[partner];
            bool before = (va > vb) || (va == vb && ia < ib);
            bool asc = ((l & k) == 0);
            bool doSwap = asc ? (!before) : before;
            if (doSwap) { v[l] = vb; v[partner] = va; ix[l] = ib; ix[partner] = ia; }
            __syncthreads();
        }
    }
    lams[t] = v[t]; lams[t + 1024] = v[t + 1024];
    order[t] = ix[t]; order[t + 1024] = ix[t + 1024];
}

__global__ void k_out(const float* __restrict__ Vm, const double* __restrict__ lams,
                      const int* __restrict__ order, float* __restrict__ out) {
    int c = blockIdx.x, t = threadIdx.x;
    int col = order[c];
    __shared__ float rv[256]; __shared__ int ri[256];
    float bv = -1.f; int bidx = N;
    for (int i = t; i < N; i += 256) {
        float av = fabsf(Vm[(size_t)i * N + col]);
        if (av > bv || (av == bv && i < bidx)) { bv = av; bidx = i; }
    }
    rv[t] = bv; ri[t] = bidx;
    __syncthreads();
    for (int off = 128; off; off >>= 1) {
        if (t < off) {
            if (rv[t + off] > rv[t] || (rv[t + off] == rv[t] && ri[t + off] < ri[t])) {
                rv[t] = rv[t + off]; ri[t] = ri[t + off];
            }
        }
        __syncthreads();
    }
    float sv = Vm[(size_t)ri[0] * N + col];
    float s = (sv > 0.f) ? 1.f : ((sv < 0.f) ? -1.f : 0.f);
    double lv = lams[c];
    float f = s * (float)sqrt(lv > 0.0 ? lv : 0.0);
    for (int i = t; i < N; i += 256) out[(size_t)i * NC + c] = Vm[(size_t)i * N + col] * f;
}

extern "C" void kernel_launch(void* const* d_in, const int* in_sizes, int n_in,
                              void* d_out, int out_size, void* d_ws, size_t ws_size,
                              hipStream_t stream) {
    (void)in_sizes; (void)n_in; (void)out_size; (void)ws_size;
    const float* X = (const float*)d_in[0];
    float* out = (float*)d_out;

    double* rm  = (double*)d_ws;                 // N
    double* gm  = rm + N;                        // 1 (+7 pad)
    double* lam = gm + 8;                        // N
    double* lams= lam + N;                       // N
    double* A   = lams + N;                      // N*N fp64
    double* qb  = A + (size_t)N * N;             // 2 * NPAIRS*1024 fp64 (double-buffered)
    float* Dg   = (float*)(qb + 2 * (size_t)NPAIRS * 1024); // N*N f32
    float* Vm   = Dg + (size_t)N * N;            // N*N f32
    float* sq   = Vm + (size_t)N * N;            // N
    int* order  = (int*)(sq + N);                // N
    int* qfl    = order + N;                     // 2 * NPAIRS
    unsigned* flags = (unsigned*)(qfl + 2 * NPAIRS); // 3
    float* dist = (float*)A;                     // alias: dist dies before A is born

    // 1. pairwise distances
    k_rowsq<<<N / 4, 256, 0, stream>>>(X, sq);
    k_dist<<<dim3(32, 32), 256, 0, stream>>>(X, sq, dist);

    // 2. KNN graph
    k_knn<<<N, 256, 0, stream>>>(dist, Dg);
    k_symdiag<<<(N * N) / 256, 256, 0, stream>>>(Dg);

    // 3. blocked Floyd-Warshall
    for (int kb = 0; kb < N / 64; kb++) {
        k_fw12<<<63, 256, 0, stream>>>(Dg, kb);
        k_fw3<<<dim3(32, 32), 256, 0, stream>>>(Dg, kb);
    }

    // 4. double centering -> B (fp64)
    k_rowmean<<<N, 256, 0, stream>>>(Dg, rm);
    k_grand<<<1, 256, 0, stream>>>(rm, gm);
    k_buildB<<<(N * N) / 256, 256, 0, stream>>>(Dg, rm, gm, A);
    k_setV<<<(N * N) / 256, 256, 0, stream>>>(Vm);
    k_initflags<<<1, 1, 0, stream>>>(flags);

    // 5. two-sided block Jacobi; V-apply of round g-1 overlaps local of round g
    int g = 0;
    for (int sw = 0; sw < NSWEEPS; sw++) {
        k_sweepctl<<<1, 1, 0, stream>>>(flags);
        for (int r = 0; r < NB - 1; r++, g++) {
            int par = g & 1;
            int pendR = (g == 0) ? -1 : ((g - 1) % (NB - 1));
            int pendP = (g - 1) & 1;
            k_localv<<<NPAIRS + NVS, 256, 0, stream>>>(A, Vm, qb, qfl, flags, r, par, pendR, pendP);
            k_tri<<<NTRI, 256, 0, stream>>>(A, qb, qfl, flags, r, par);
        }
    }
    // drain last round's V-apply
    {
        int glast = NSWEEPS * (NB - 1) - 1;
        k_vdrain<<<NVS, 256, 0, stream>>>(Vm, qb, qfl, glast % (NB - 1), glast & 1);
    }

    // 6. sort eigenvalues, sign-fix, scale, write output
    k_lambda<<<N / 256, 256, 0, stream>>>(A, lam);
    k_sort<<<1, 1024, 0, stream>>>(lam, lams, order);
    k_out<<<NC, 256, 0, stream>>>(Vm, lams, order, out);
}

// Round 4
// 81505.719 us; speedup vs baseline: 3.2311x; 1.1617x over previous
//
#include <hip/hip_runtime.h>
#include <math.h>

#define N 2048
#define DIMS 784
#define BIGV 1.0e6f
#define NC 784

// two-sided block Jacobi config: 128 teams of width 16, 32x32 local tiles
#define NB 128
#define NPAIRS 64
#define NSWEEPS 18
#define NTRI 2016      // 64*63/2 upper-tri pair tiles
#define NVS  2048      // 64 pairs * 32 V row-stripes

typedef __attribute__((ext_vector_type(4))) double d4_t;

// round-robin pairing over nteams: round r in [0,nteams-1), pair m in [0,nteams/2)
__device__ __forceinline__ void rr_pairN(int r, int m, int nteams, int& bi, int& bj) {
    int n1 = nteams - 1;
    if (m == 0) { bi = n1; bj = r % n1; }
    else { bi = (r + m) % n1; bj = (r - m + n1) % n1; }
}

// ---------------- distances ----------------
__global__ void k_rowsq(const float* __restrict__ X, float* __restrict__ sq) {
    int wave = threadIdx.x >> 6, lane = threadIdx.x & 63;
    int row = blockIdx.x * 4 + wave;
    const float* xr = X + (size_t)row * DIMS;
    float s = 0.f;
    for (int k = lane; k < DIMS; k += 64) { float v = xr[k]; s += v * v; }
    for (int off = 32; off; off >>= 1) s += __shfl_down(s, off);
    if (lane == 0) sq[row] = s;
}

__global__ void __launch_bounds__(256) k_dist(const float* __restrict__ X,
                                              const float* __restrict__ sq,
                                              float* __restrict__ out) {
    __shared__ float As[64][17], Bs[64][17];
    int ti = blockIdx.y, tj = blockIdx.x, t = threadIdx.x;
    int tx = t & 15, ty = t >> 4;
    float acc[4][4] = {};
    for (int k0 = 0; k0 < DIMS; k0 += 16) {
        for (int e = 0; e < 4; e++) {
            int idx = t + e * 256; int r = idx >> 4, c = idx & 15;
            As[r][c] = X[(size_t)(ti * 64 + r) * DIMS + k0 + c];
            Bs[r][c] = X[(size_t)(tj * 64 + r) * DIMS + k0 + c];
        }
        __syncthreads();
        for (int k = 0; k < 16; k++) {
            float a[4], b[4];
            for (int e = 0; e < 4; e++) a[e] = As[ty * 4 + e][k];
            for (int f = 0; f < 4; f++) b[f] = Bs[tx * 4 + f][k];
            for (int e = 0; e < 4; e++)
                for (int f = 0; f < 4; f++) acc[e][f] += a[e] * b[f];
        }
        __syncthreads();
    }
    for (int e = 0; e < 4; e++)
        for (int f = 0; f < 4; f++) {
            int gi = ti * 64 + ty * 4 + e, gj = tj * 64 + tx * 4 + f;
            float d2 = sq[gi] + sq[gj] - 2.f * acc[e][f];
            out[(size_t)gi * N + gj] = sqrtf(fmaxf(d2, 0.f));
        }
}

// ---------------- KNN graph ----------------
__global__ void k_knn(const float* __restrict__ dist, float* __restrict__ G) {
    int i = blockIdx.x, t = threadIdx.x;
    float bv[6]; int bidx[6];
    for (int k = 0; k < 6; k++) { bv[k] = 3.4e38f; bidx[k] = N; }
    const float* dr = dist + (size_t)i * N;
    for (int j = t; j < N; j += 256) {
        float v = dr[j];
        bool ins = (v < bv[5]) || (v == bv[5] && j < bidx[5]);
        if (ins) {
            int k = 5;
            while (k > 0) {
                bool mv = (v < bv[k - 1]) || (v == bv[k - 1] && j < bidx[k - 1]);
                if (!mv) break;
                bv[k] = bv[k - 1]; bidx[k] = bidx[k - 1]; k--;
            }
            bv[k] = v; bidx[k] = j;
        }
    }
    __shared__ float lv[256][6]; __shared__ int li[256][6];
    for (int k = 0; k < 6; k++) { lv[t][k] = bv[k]; li[t][k] = bidx[k]; }
    __syncthreads();
    for (int off = 128; off >= 1; off >>= 1) {
        if (t < off) {
            float av[6], cv[6]; int ai[6], ci[6];
            for (int k = 0; k < 6; k++) { av[k] = lv[t][k]; ai[k] = li[t][k]; cv[k] = lv[t + off][k]; ci[k] = li[t + off][k]; }
            float mv[6]; int mi[6]; int pa = 0, pb = 0;
            for (int k = 0; k < 6; k++) {
                bool ta;
                if (pa >= 6) ta = false;
                else if (pb >= 6) ta = true;
                else ta = (av[pa] < cv[pb]) || (av[pa] == cv[pb] && ai[pa] < ci[pb]);
                if (ta) { mv[k] = av[pa]; mi[k] = ai[pa]; pa++; }
                else    { mv[k] = cv[pb]; mi[k] = ci[pb]; pb++; }
            }
            for (int k = 0; k < 6; k++) { lv[t][k] = mv[k]; li[t][k] = mi[k]; }
        }
        __syncthreads();
    }
    float sv[6]; int si[6];
    for (int k = 0; k < 6; k++) { sv[k] = lv[0][k]; si[k] = li[0][k]; }
    for (int j = t; j < N; j += 256) {
        float val = BIGV;
        for (int k = 0; k < 6; k++) if (j == si[k]) val = sv[k];
        G[(size_t)i * N + j] = val;
    }
}

__global__ void k_symdiag(float* __restrict__ G) {
    int idx = blockIdx.x * 256 + threadIdx.x;
    int i = idx >> 11, j = idx & 2047;
    if (i == j) { G[idx] = 0.f; return; }
    if (j > i) {
        float a = G[(size_t)i * N + j], b = G[(size_t)j * N + i];
        float m = fminf(a, b);
        G[(size_t)i * N + j] = m; G[(size_t)j * N + i] = m;
    }
}

// ---------------- blocked Floyd-Warshall ----------------
__global__ void __launch_bounds__(256) k_fw12(float* __restrict__ D, int kb) {
    __shared__ float KK[64][65], C[64][65];
    int bx = blockIdx.x, t = threadIdx.x;
    for (int e = 0; e < 16; e++) { int idx = t + e * 256; int r = idx >> 6, c = idx & 63;
        KK[r][c] = D[(size_t)(kb * 64 + r) * N + kb * 64 + c]; }
    __syncthreads();
    int r0 = t >> 2, c0 = (t & 3) * 16;
    for (int k = 0; k < 64; k++) {
        float dk = KK[r0][k];
        for (int c = 0; c < 16; c++) KK[r0][c0 + c] = fminf(KK[r0][c0 + c], dk + KK[k][c0 + c]);
        __syncthreads();
    }
    if (bx == 62) {
        for (int e = 0; e < 16; e++) { int idx = t + e * 256; int r = idx >> 6, c = idx & 63;
            D[(size_t)(kb * 64 + r) * N + kb * 64 + c] = KK[r][c]; }
        return;
    }
    bool rowstripe = bx < 31;
    int o = rowstripe ? bx : bx - 31;
    o += (o >= kb) ? 1 : 0;
    int baseR = rowstripe ? kb : o;
    int baseC = rowstripe ? o : kb;
    for (int e = 0; e < 16; e++) { int idx = t + e * 256; int r = idx >> 6, c = idx & 63;
        C[r][c] = D[(size_t)(baseR * 64 + r) * N + baseC * 64 + c]; }
    __syncthreads();
    if (rowstripe) {
        for (int k = 0; k < 64; k++) {
            float dk = KK[r0][k];
            for (int c = 0; c < 16; c++) C[r0][c0 + c] = fminf(C[r0][c0 + c], dk + C[k][c0 + c]);
            __syncthreads();
        }
    } else {
        for (int k = 0; k < 64; k++) {
            float dk = C[r0][k];
            for (int c = 0; c < 16; c++) C[r0][c0 + c] = fminf(C[r0][c0 + c], dk + KK[k][c0 + c]);
            __syncthreads();
        }
    }
    for (int e = 0; e < 16; e++) { int idx = t + e * 256; int r = idx >> 6, c = idx & 63;
        D[(size_t)(baseR * 64 + r) * N + baseC * 64 + c] = C[r][c]; }
}

__global__ void __launch_bounds__(256) k_fw3(float* __restrict__ D, int kb) {
    int bi = blockIdx.y, bj = blockIdx.x;
    if (bi == kb || bj == kb) return;
    __shared__ float R[64][65], Cl[64][65];
    int t = threadIdx.x;
    for (int e = 0; e < 16; e++) { int idx = t + e * 256; int r = idx >> 6, c = idx & 63;
        R[r][c]  = D[(size_t)(bi * 64 + r) * N + kb * 64 + c];
        Cl[r][c] = D[(size_t)(kb * 64 + r) * N + bj * 64 + c]; }
    __syncthreads();
    int r0 = (t >> 4) * 4, c0 = (t & 15) * 4;
    float acc[4][4];
    for (int e = 0; e < 4; e++) for (int f = 0; f < 4; f++) acc[e][f] = 3.4e38f;
    for (int k = 0; k < 64; k++) {
        float a[4], b[4];
        for (int e = 0; e < 4; e++) a[e] = R[r0 + e][k];
        for (int f = 0; f < 4; f++) b[f] = Cl[k][c0 + f];
        for (int e = 0; e < 4; e++)
            for (int f = 0; f < 4; f++) acc[e][f] = fminf(acc[e][f], a[e] + b[f]);
    }
    for (int e = 0; e < 4; e++)
        for (int f = 0; f < 4; f++) {
            size_t off = (size_t)(bi * 64 + r0 + e) * N + bj * 64 + c0 + f;
            D[off] = fminf(D[off], acc[e][f]);
        }
}

// ---------------- double centering ----------------
__global__ void k_rowmean(const float* __restrict__ D, double* __restrict__ rm) {
    int i = blockIdx.x, t = threadIdx.x;
    const float* dr = D + (size_t)i * N;
    double s = 0;
    for (int j = t; j < N; j += 256) { double d = (double)dr[j]; s += d * d; }
    __shared__ double red[256];
    red[t] = s; __syncthreads();
    for (int off = 128; off; off >>= 1) { if (t < off) red[t] += red[t + off]; __syncthreads(); }
    if (t == 0) rm[i] = red[0] / (double)N;
}

__global__ void k_grand(const double* __restrict__ rm, double* __restrict__ gm) {
    int t = threadIdx.x;
    double s = 0;
    for (int i = t; i < N; i += 256) s += rm[i];
    __shared__ double red[256];
    red[t] = s; __syncthreads();
    for (int off = 128; off; off >>= 1) { if (t < off) red[t] += red[t + off]; __syncthreads(); }
    if (t == 0) gm[0] = red[0] / (double)N;
}

__global__ void k_buildB(const float* __restrict__ D, const double* __restrict__ rm,
                         const double* __restrict__ gm, double* __restrict__ A) {
    int idx = blockIdx.x * 256 + threadIdx.x;
    int i = idx >> 11, j = idx & 2047;
    double d = (double)D[idx];
    A[idx] = -0.5 * (d * d - rm[i] - rm[j] + gm[0]);
}

__global__ void k_setV(float* __restrict__ V) {
    int idx = blockIdx.x * 256 + threadIdx.x;
    int i = idx >> 11, j = idx & 2047;
    V[idx] = (i == j) ? 1.f : 0.f;
}

// ---------------- Jacobi control ----------------
__global__ void k_initflags(unsigned* flags) { flags[0] = 0u; flags[1] = 0u; flags[2] = 0u; }
// once per sweep: convergence check on previous sweep's accumulated maxima, then reset
__global__ void k_sweepctl(unsigned* flags) {
    if (!flags[2]) {
        float mo = __uint_as_float(flags[0]), md = __uint_as_float(flags[1]);
        if (md > 0.f && mo <= 2e-9f * md) { flags[2] = 1u; return; }
        flags[0] = 0u; flags[1] = 0u;
    }
}

// ---- V <- V*Q for one 64-row stripe; shared by k_localv / k_vdrain ----
__device__ __forceinline__ void vapply_task(float* __restrict__ V, const double* __restrict__ qbP,
                                            const int* __restrict__ qp, int rnd, int task, int t) {
    int p = task >> 5, rt = task & 31;
    if (!qp[p]) return;
    __shared__ float Qs[32][33], Tv[64][33];
    int bi, bj; rr_pairN(rnd, p, NB, bi, bj);
    for (int e = 0; e < 4; e++) {
        int idx = t + e * 256; int a = idx >> 5, c = idx & 31;
        Qs[a][c] = (float)qbP[(size_t)p * 1024 + idx];
    }
    for (int e = 0; e < 8; e++) {
        int idx = t + e * 256; int a = idx >> 5, c = idx & 31;
        int gc = (c < 16) ? bi * 16 + c : bj * 16 + (c - 16);
        Tv[a][c] = V[(size_t)(rt * 64 + a) * N + gc];
    }
    __syncthreads();
    int r0 = (t >> 4) * 4, c0 = (t & 15) * 2;
    float acc[4][2] = {};
    for (int y = 0; y < 32; y++) {
        float q0 = Qs[y][c0], q1 = Qs[y][c0 + 1];
        for (int e = 0; e < 4; e++) {
            float vv = Tv[r0 + e][y];
            acc[e][0] += vv * q0; acc[e][1] += vv * q1;
        }
    }
    for (int e = 0; e < 4; e++)
        for (int f = 0; f < 2; f++) {
            int x = c0 + f;
            int gc = (x < 16) ? bi * 16 + x : bj * 16 + (x - 16);
            V[(size_t)(rt * 64 + r0 + e) * N + gc] = acc[e][f];
        }
}

// ---------------- local 32x32 Jacobi (blocks 0..63) || V-apply of pending round ----------------
// No inter-role dependency: local(r) touches A + qb/qfl[par]; V-apply(r-1) touches V + qb/qfl[pendP].
__global__ void __launch_bounds__(256) k_localv(double* __restrict__ A, float* __restrict__ V,
                                                double* __restrict__ qb,
                                                int* __restrict__ qfl, unsigned* __restrict__ flags,
                                                int round, int par, int pendR, int pendP) {
    int t = threadIdx.x;
    if (blockIdx.x >= NPAIRS) {
        if (pendR < 0) return;
        vapply_task(V, qb + (size_t)pendP * (NPAIRS * 1024), qfl + pendP * NPAIRS,
                    pendR, (int)blockIdx.x - NPAIRS, t);
        return;
    }
    int p = blockIdx.x;
    double* qbC = qb + (size_t)par * (NPAIRS * 1024);
    int* qflC = qfl + par * NPAIRS;
    if (flags[2]) { if (t == 0) qflC[p] = 0; return; }
    __shared__ double M[32][33], Q[32][33];
    __shared__ double cA[16], sA[16];
    __shared__ int ppA[16], qqA[16];
    __shared__ float red1[256], red2[256];
    __shared__ int everr;
    int bi, bj; rr_pairN(round, p, NB, bi, bj);

    float offm = 0.f, diagm = 0.f;
    for (int e = 0; e < 4; e++) {
        int idx = t + e * 256; int x = idx >> 5, y = idx & 31;
        int gr = (x < 16) ? bi * 16 + x : bj * 16 + (x - 16);
        int gc = (y < 16) ? bi * 16 + y : bj * 16 + (y - 16);
        double v = A[(size_t)gr * N + gc];
        M[x][y] = v;
        float av = (float)fabs(v);
        if (x == y) diagm = fmaxf(diagm, av); else offm = fmaxf(offm, av);
        Q[x][y] = (x == y) ? 1.0 : 0.0;
    }
    red1[t] = offm; red2[t] = diagm;
    if (t == 0) everr = 0;
    __syncthreads();
    for (int off = 128; off; off >>= 1) {
        if (t < off) { red1[t] = fmaxf(red1[t], red1[t + off]); red2[t] = fmaxf(red2[t], red2[t + off]); }
        __syncthreads();
    }
    float dmaxf = red2[0], off0 = red1[0];
    if (t == 0) { atomicMax(flags + 0, __float_as_uint(off0)); atomicMax(flags + 1, __float_as_uint(dmaxf)); }
    double dmax = (double)dmaxf;
    if ((double)off0 <= 1e-9 * dmax) { if (t == 0) qflC[p] = 0; return; }
    double thr = fmax(1e-13 * dmax, 1e-5 * (double)off0);

    for (int ir = 0; ir < 31; ir++) {
        if (t < 16) {
            int pp, qq; rr_pairN(ir, t, 32, pp, qq);
            double app = M[pp][pp], aqq = M[qq][qq], apq = M[pp][qq];
            double c = 1.0, sn = 0.0;
            if (fabs(apq) > thr) {
                double tau = (aqq - app) / (2.0 * apq);
                double tt2 = ((tau >= 0.0) ? 1.0 : -1.0) / (fabs(tau) + sqrt(1.0 + tau * tau));
                c = 1.0 / sqrt(1.0 + tt2 * tt2);
                sn = tt2 * c;
                everr = 1;
            }
            ppA[t] = pp; qqA[t] = qq; cA[t] = c; sA[t] = sn;
        }
        __syncthreads();
        // col updates: M <- M*J, Q <- Q*J  (512 slots, 2/thread)
        for (int e = 0; e < 2; e++) {
            int slot = t + e * 256; int mm = slot >> 5, k = slot & 31;
            double sn = sA[mm];
            if (sn != 0.0) {
                int pp = ppA[mm], qq = qqA[mm]; double c = cA[mm];
                double a = M[k][pp], b = M[k][qq];
                M[k][pp] = c * a - sn * b; M[k][qq] = sn * a + c * b;
                a = Q[k][pp]; b = Q[k][qq];
                Q[k][pp] = c * a - sn * b; Q[k][qq] = sn * a + c * b;
            }
        }
        __syncthreads();
        // row updates: M <- J^T * M
        for (int e = 0; e < 2; e++) {
            int slot = t + e * 256; int mm = slot >> 5, k = slot & 31;
            double sn = sA[mm];
            if (sn != 0.0) {
                int pp = ppA[mm], qq = qqA[mm]; double c = cA[mm];
                double a = M[pp][k], b = M[qq][k];
                M[pp][k] = c * a - sn * b; M[qq][k] = sn * a + c * b;
            }
        }
        __syncthreads();
    }
    int ev = everr;
    if (t == 0) qflC[p] = ev;
    if (ev) {
        for (int e = 0; e < 4; e++) {
            int idx = t + e * 256; int x = idx >> 5, y = idx & 31;
            qbC[(size_t)p * 1024 + idx] = Q[x][y];
            int gr = (x < 16) ? bi * 16 + x : bj * 16 + (x - 16);
            int gc = (y < 16) ? bi * 16 + y : bj * 16 + (y - 16);
            A[(size_t)gr * N + gc] = M[x][y];
        }
    }
}

// ---------------- tri-apply: A <- Qr^T A Qc on upper-tri pair tiles (fp64 MFMA) ----------------
// One wave per 16x16 output quadrant; K=32 in 8 MFMA(16x16x4) steps.
// Layouts (gfx950, shape-determined): A[i][k]: i=lane&15,k=lane>>4; B[k][j]: j=lane&15,k=lane>>4;
// D[i][j]: j=lane&15, i=(lane>>4)*4+v.
__global__ void __launch_bounds__(256) k_tri(double* __restrict__ A,
                                             const double* __restrict__ qb,
                                             const int* __restrict__ qfl,
                                             const unsigned* __restrict__ flags,
                                             int round, int par) {
    if (flags[2]) return;
    const double* qbC = qb + (size_t)par * (NPAIRS * 1024);
    const int* qflC = qfl + par * NPAIRS;
    int t = threadIdx.x;
    int task = blockIdx.x;
    int pr = 0, rem = task;
    while (rem >= 63 - pr) { rem -= 63 - pr; pr++; }
    int pc = pr + 1 + rem;
    int fr = qflC[pr], fc = qflC[pc];
    if (!fr && !fc) return;
    __shared__ double T[32][33], Qb[32][33];
    int bir, bjr, bic, bjc;
    rr_pairN(round, pr, NB, bir, bjr);
    rr_pairN(round, pc, NB, bic, bjc);
    for (int e = 0; e < 4; e++) {
        int idx = t + e * 256; int a = idx >> 5, b = idx & 31;
        if (fr) Qb[a][b] = qbC[(size_t)pr * 1024 + idx];
        int gr = (a < 16) ? bir * 16 + a : bjr * 16 + (a - 16);
        int gc = (b < 16) ? bic * 16 + b : bjc * 16 + (b - 16);
        T[a][b] = A[(size_t)gr * N + gc];
    }
    __syncthreads();
    int wv = t >> 6, ln = t & 63;
    int i0 = (wv >> 1) * 16, j0 = (wv & 1) * 16;   // this wave's 16x16 output quadrant
    int li = ln & 15, lk = ln >> 4;
    if (fr) {
        // C1 = Qr^T * T : A_mat[i][y] = Qr[y][i], B_mat[y][j] = T[y][j]
        d4_t d = {0.0, 0.0, 0.0, 0.0};
        #pragma unroll
        for (int y0 = 0; y0 < 32; y0 += 4) {
            double a = Qb[y0 + lk][i0 + li];
            double b = T[y0 + lk][j0 + li];
            d = __builtin_amdgcn_mfma_f64_16x16x4f64(a, b, d, 0, 0, 0);
        }
        __syncthreads();
        #pragma unroll
        for (int v = 0; v < 4; v++) T[i0 + lk * 4 + v][j0 + li] = d[v];
        __syncthreads();
    }
    if (fc) {
        for (int e = 0; e < 4; e++) {
            int idx = t + e * 256; int a = idx >> 5, b = idx & 31;
            Qb[a][b] = qbC[(size_t)pc * 1024 + idx];
        }
        __syncthreads();
        // C2 = T * Qc : A_mat[i][y] = T[i][y], B_mat[y][j] = Qc[y][j]
        d4_t d = {0.0, 0.0, 0.0, 0.0};
        #pragma unroll
        for (int y0 = 0; y0 < 32; y0 += 4) {
            double a = T[i0 + li][y0 + lk];
            double b = Qb[y0 + lk][j0 + li];
            d = __builtin_amdgcn_mfma_f64_16x16x4f64(a, b, d, 0, 0, 0);
        }
        __syncthreads();
        #pragma unroll
        for (int v = 0; v < 4; v++) T[i0 + lk * 4 + v][j0 + li] = d[v];
        __syncthreads();
    }
    for (int e = 0; e < 4; e++) {
        int idx = t + e * 256; int a = idx >> 5, b = idx & 31;
        int gr = (a < 16) ? bir * 16 + a : bjr * 16 + (a - 16);
        int gc = (b < 16) ? bic * 16 + b : bjc * 16 + (b - 16);
        A[(size_t)gr * N + gc] = T[a][b];
        int gr2 = (a < 16) ? bic * 16 + a : bjc * 16 + (a - 16);
        int gc2 = (b < 16) ? bir * 16 + b : bjr * 16 + (b - 16);
        A[(size_t)gr2 * N + gc2] = T[b][a];
    }
}

// drain: V-apply of the final round
__global__ void __launch_bounds__(256) k_vdrain(float* __restrict__ V, const double* __restrict__ qb,
                                                const int* __restrict__ qfl, int rnd, int par) {
    vapply_task(V, qb + (size_t)par * (NPAIRS * 1024), qfl + par * NPAIRS,
                rnd, (int)blockIdx.x, threadIdx.x);
}

// ---------------- epilogue ----------------
__global__ void k_lambda(const double* __restrict__ A, double* __restrict__ lam) {
    int i = blockIdx.x * 256 + threadIdx.x;
    if (i < N) lam[i] = A[(size_t)i * N + i];
}

__global__ void __launch_bounds__(1024) k_sort(const double* __restrict__ lam,
                                               double* __restrict__ lams, int* __restrict__ order) {
    __shared__ double v[2048]; __shared__ int ix[2048];
    int t = threadIdx.x;
    v[t] = lam[t]; v[t + 1024] = lam[t + 1024];
    ix[t] = t; ix[t + 1024] = t + 1024;
    __syncthreads();
    for (int k = 2; k <= 2048; k <<= 1) {
        for (int j = k >> 1; j > 0; j >>= 1) {
            int l = ((t & ~(j - 1)) << 1) | (t & (j - 1));
            int partner = l | j;
            double va = v[l], vb = v[partner]; int ia = ix[l], ib = ix[partner];
            bool before = (va > vb) || (va == vb && ia < ib);
            bool asc = ((l & k) == 0);
            bool doSwap = asc ? (!before) : before;
            if (doSwap) { v[l] = vb; v[partner] = va; ix[l] = ib; ix[partner] = ia; }
            __syncthreads();
        }
    }
    lams[t] = v[t]; lams[t + 1024] = v[t + 1024];
    order[t] = ix[t]; order[t + 1024] = ix[t + 1024];
}

__global__ void k_out(const float* __restrict__ Vm, const double* __restrict__ lams,
                      const int* __restrict__ order, float* __restrict__ out) {
    int c = blockIdx.x, t = threadIdx.x;
    int col = order[c];
    __shared__ float rv[256]; __shared__ int ri[256];
    float bv = -1.f; int bidx = N;
    for (int i = t; i < N; i += 256) {
        float av = fabsf(Vm[(size_t)i * N + col]);
        if (av > bv || (av == bv && i < bidx)) { bv = av; bidx = i; }
    }
    rv[t] = bv; ri[t] = bidx;
    __syncthreads();
    for (int off = 128; off; off >>= 1) {
        if (t < off) {
            if (rv[t + off] > rv[t] || (rv[t + off] == rv[t] && ri[t + off] < ri[t])) {
                rv[t] = rv[t + off]; ri[t] = ri[t + off];
            }
        }
        __syncthreads();
    }
    float sv = Vm[(size_t)ri[0] * N + col];
    float s = (sv > 0.f) ? 1.f : ((sv < 0.f) ? -1.f : 0.f);
    double lv = lams[c];
    float f = s * (float)sqrt(lv > 0.0 ? lv : 0.0);
    for (int i = t; i < N; i += 256) out[(size_t)i * NC + c] = Vm[(size_t)i * N + col] * f;
}

extern "C" void kernel_launch(void* const* d_in, const int* in_sizes, int n_in,
                              void* d_out, int out_size, void* d_ws, size_t ws_size,
                              hipStream_t stream) {
    (void)in_sizes; (void)n_in; (void)out_size; (void)ws_size;
    const float* X = (const float*)d_in[0];
    float* out = (float*)d_out;

    double* rm  = (double*)d_ws;                 // N
    double* gm  = rm + N;                        // 1 (+7 pad)
    double* lam = gm + 8;                        // N
    double* lams= lam + N;                       // N
    double* A   = lams + N;                      // N*N fp64
    double* qb  = A + (size_t)N * N;             // 2 * NPAIRS*1024 fp64 (double-buffered)
    float* Dg   = (float*)(qb + 2 * (size_t)NPAIRS * 1024); // N*N f32
    float* Vm   = Dg + (size_t)N * N;            // N*N f32
    float* sq   = Vm + (size_t)N * N;            // N
    int* order  = (int*)(sq + N);                // N
    int* qfl    = order + N;                     // 2 * NPAIRS
    unsigned* flags = (unsigned*)(qfl + 2 * NPAIRS); // 3
    float* dist = (float*)A;                     // alias: dist dies before A is born

    // 1. pairwise distances
    k_rowsq<<<N / 4, 256, 0, stream>>>(X, sq);
    k_dist<<<dim3(32, 32), 256, 0, stream>>>(X, sq, dist);

    // 2. KNN graph
    k_knn<<<N, 256, 0, stream>>>(dist, Dg);
    k_symdiag<<<(N * N) / 256, 256, 0, stream>>>(Dg);

    // 3. blocked Floyd-Warshall
    for (int kb = 0; kb < N / 64; kb++) {
        k_fw12<<<63, 256, 0, stream>>>(Dg, kb);
        k_fw3<<<dim3(32, 32), 256, 0, stream>>>(Dg, kb);
    }

    // 4. double centering -> B (fp64)
    k_rowmean<<<N, 256, 0, stream>>>(Dg, rm);
    k_grand<<<1, 256, 0, stream>>>(rm, gm);
    k_buildB<<<(N * N) / 256, 256, 0, stream>>>(Dg, rm, gm, A);
    k_setV<<<(N * N) / 256, 256, 0, stream>>>(Vm);
    k_initflags<<<1, 1, 0, stream>>>(flags);

    // 5. two-sided block Jacobi; V-apply of round g-1 overlaps local of round g
    int g = 0;
    for (int sw = 0; sw < NSWEEPS; sw++) {
        k_sweepctl<<<1, 1, 0, stream>>>(flags);
        for (int r = 0; r < NB - 1; r++, g++) {
            int par = g & 1;
            int pendR = (g == 0) ? -1 : ((g - 1) % (NB - 1));
            int pendP = (g - 1) & 1;
            k_localv<<<NPAIRS + NVS, 256, 0, stream>>>(A, Vm, qb, qfl, flags, r, par, pendR, pendP);
            k_tri<<<NTRI, 256, 0, stream>>>(A, qb, qfl, flags, r, par);
        }
    }
    // drain last round's V-apply
    {
        int glast = NSWEEPS * (NB - 1) - 1;
        k_vdrain<<<NVS, 256, 0, stream>>>(Vm, qb, qfl, glast % (NB - 1), glast & 1);
    }

    // 6. sort eigenvalues, sign-fix, scale, write output
    k_lambda<<<N / 256, 256, 0, stream>>>(A, lam);
    k_sort<<<1, 1024, 0, stream>>>(lam, lams, order);
    k_out<<<NC, 256, 0, stream>>>(Vm, lams, order, out);
}

// Round 5
// 80354.651 us; speedup vs baseline: 3.2774x; 1.0143x over previous
//
#include <hip/hip_runtime.h>
#include <math.h>

#define N 2048
#define DIMS 784
#define BIGV 1.0e6f
#define NC 784

// two-sided block Jacobi config: 128 teams of width 16, 32x32 local tiles
#define NB 128
#define NPAIRS 64
#define NSWEEPS 18
#define NTRI 2016      // 64*63/2 upper-tri pair tiles
#define NVS  2048      // 64 pairs * 32 V row-stripes

typedef __attribute__((ext_vector_type(4))) double d4_t;

// round-robin pairing over nteams: round r in [0,nteams-1), pair m in [0,nteams/2)
__device__ __forceinline__ void rr_pairN(int r, int m, int nteams, int& bi, int& bj) {
    int n1 = nteams - 1;
    if (m == 0) { bi = n1; bj = r % n1; }
    else { bi = (r + m) % n1; bj = (r - m + n1) % n1; }
}

// A is stored CANONICALLY: 16x16 team-sub-block (u,v) is valid only at u<=v.
// Readers of (u,v) with u>v read canonical (v,u) row-major (coalesced) and
// transpose on the LDS store. 256 threads cover one 16x16 block (rr=t>>4, cc=t&15).

// ---------------- distances ----------------
__global__ void k_rowsq(const float* __restrict__ X, float* __restrict__ sq) {
    int wave = threadIdx.x >> 6, lane = threadIdx.x & 63;
    int row = blockIdx.x * 4 + wave;
    const float* xr = X + (size_t)row * DIMS;
    float s = 0.f;
    for (int k = lane; k < DIMS; k += 64) { float v = xr[k]; s += v * v; }
    for (int off = 32; off; off >>= 1) s += __shfl_down(s, off);
    if (lane == 0) sq[row] = s;
}

__global__ void __launch_bounds__(256) k_dist(const float* __restrict__ X,
                                              const float* __restrict__ sq,
                                              float* __restrict__ out) {
    __shared__ float As[64][17], Bs[64][17];
    int ti = blockIdx.y, tj = blockIdx.x, t = threadIdx.x;
    int tx = t & 15, ty = t >> 4;
    float acc[4][4] = {};
    for (int k0 = 0; k0 < DIMS; k0 += 16) {
        for (int e = 0; e < 4; e++) {
            int idx = t + e * 256; int r = idx >> 4, c = idx & 15;
            As[r][c] = X[(size_t)(ti * 64 + r) * DIMS + k0 + c];
            Bs[r][c] = X[(size_t)(tj * 64 + r) * DIMS + k0 + c];
        }
        __syncthreads();
        for (int k = 0; k < 16; k++) {
            float a[4], b[4];
            for (int e = 0; e < 4; e++) a[e] = As[ty * 4 + e][k];
            for (int f = 0; f < 4; f++) b[f] = Bs[tx * 4 + f][k];
            for (int e = 0; e < 4; e++)
                for (int f = 0; f < 4; f++) acc[e][f] += a[e] * b[f];
        }
        __syncthreads();
    }
    for (int e = 0; e < 4; e++)
        for (int f = 0; f < 4; f++) {
            int gi = ti * 64 + ty * 4 + e, gj = tj * 64 + tx * 4 + f;
            float d2 = sq[gi] + sq[gj] - 2.f * acc[e][f];
            out[(size_t)gi * N + gj] = sqrtf(fmaxf(d2, 0.f));
        }
}

// ---------------- KNN graph ----------------
__global__ void k_knn(const float* __restrict__ dist, float* __restrict__ G) {
    int i = blockIdx.x, t = threadIdx.x;
    float bv[6]; int bidx[6];
    for (int k = 0; k < 6; k++) { bv[k] = 3.4e38f; bidx[k] = N; }
    const float* dr = dist + (size_t)i * N;
    for (int j = t; j < N; j += 256) {
        float v = dr[j];
        bool ins = (v < bv[5]) || (v == bv[5] && j < bidx[5]);
        if (ins) {
            int k = 5;
            while (k > 0) {
                bool mv = (v < bv[k - 1]) || (v == bv[k - 1] && j < bidx[k - 1]);
                if (!mv) break;
                bv[k] = bv[k - 1]; bidx[k] = bidx[k - 1]; k--;
            }
            bv[k] = v; bidx[k] = j;
        }
    }
    __shared__ float lv[256][6]; __shared__ int li[256][6];
    for (int k = 0; k < 6; k++) { lv[t][k] = bv[k]; li[t][k] = bidx[k]; }
    __syncthreads();
    for (int off = 128; off >= 1; off >>= 1) {
        if (t < off) {
            float av[6], cv[6]; int ai[6], ci[6];
            for (int k = 0; k < 6; k++) { av[k] = lv[t][k]; ai[k] = li[t][k]; cv[k] = lv[t + off][k]; ci[k] = li[t + off][k]; }
            float mv[6]; int mi[6]; int pa = 0, pb = 0;
            for (int k = 0; k < 6; k++) {
                bool ta;
                if (pa >= 6) ta = false;
                else if (pb >= 6) ta = true;
                else ta = (av[pa] < cv[pb]) || (av[pa] == cv[pb] && ai[pa] < ci[pb]);
                if (ta) { mv[k] = av[pa]; mi[k] = ai[pa]; pa++; }
                else    { mv[k] = cv[pb]; mi[k] = ci[pb]; pb++; }
            }
            for (int k = 0; k < 6; k++) { lv[t][k] = mv[k]; li[t][k] = mi[k]; }
        }
        __syncthreads();
    }
    float sv[6]; int si[6];
    for (int k = 0; k < 6; k++) { sv[k] = lv[0][k]; si[k] = li[0][k]; }
    for (int j = t; j < N; j += 256) {
        float val = BIGV;
        for (int k = 0; k < 6; k++) if (j == si[k]) val = sv[k];
        G[(size_t)i * N + j] = val;
    }
}

__global__ void k_symdiag(float* __restrict__ G) {
    int idx = blockIdx.x * 256 + threadIdx.x;
    int i = idx >> 11, j = idx & 2047;
    if (i == j) { G[idx] = 0.f; return; }
    if (j > i) {
        float a = G[(size_t)i * N + j], b = G[(size_t)j * N + i];
        float m = fminf(a, b);
        G[(size_t)i * N + j] = m; G[(size_t)j * N + i] = m;
    }
}

// ---------------- blocked Floyd-Warshall ----------------
__global__ void __launch_bounds__(256) k_fw12(float* __restrict__ D, int kb) {
    __shared__ float KK[64][65], C[64][65];
    int bx = blockIdx.x, t = threadIdx.x;
    for (int e = 0; e < 16; e++) { int idx = t + e * 256; int r = idx >> 6, c = idx & 63;
        KK[r][c] = D[(size_t)(kb * 64 + r) * N + kb * 64 + c]; }
    __syncthreads();
    int r0 = t >> 2, c0 = (t & 3) * 16;
    for (int k = 0; k < 64; k++) {
        float dk = KK[r0][k];
        for (int c = 0; c < 16; c++) KK[r0][c0 + c] = fminf(KK[r0][c0 + c], dk + KK[k][c0 + c]);
        __syncthreads();
    }
    if (bx == 62) {
        for (int e = 0; e < 16; e++) { int idx = t + e * 256; int r = idx >> 6, c = idx & 63;
            D[(size_t)(kb * 64 + r) * N + kb * 64 + c] = KK[r][c]; }
        return;
    }
    bool rowstripe = bx < 31;
    int o = rowstripe ? bx : bx - 31;
    o += (o >= kb) ? 1 : 0;
    int baseR = rowstripe ? kb : o;
    int baseC = rowstripe ? o : kb;
    for (int e = 0; e < 16; e++) { int idx = t + e * 256; int r = idx >> 6, c = idx & 63;
        C[r][c] = D[(size_t)(baseR * 64 + r) * N + baseC * 64 + c]; }
    __syncthreads();
    if (rowstripe) {
        for (int k = 0; k < 64; k++) {
            float dk = KK[r0][k];
            for (int c = 0; c < 16; c++) C[r0][c0 + c] = fminf(C[r0][c0 + c], dk + C[k][c0 + c]);
            __syncthreads();
        }
    } else {
        for (int k = 0; k < 64; k++) {
            float dk = C[r0][k];
            for (int c = 0; c < 16; c++) C[r0][c0 + c] = fminf(C[r0][c0 + c], dk + KK[k][c0 + c]);
            __syncthreads();
        }
    }
    for (int e = 0; e < 16; e++) { int idx = t + e * 256; int r = idx >> 6, c = idx & 63;
        D[(size_t)(baseR * 64 + r) * N + baseC * 64 + c] = C[r][c]; }
}

__global__ void __launch_bounds__(256) k_fw3(float* __restrict__ D, int kb) {
    int bi = blockIdx.y, bj = blockIdx.x;
    if (bi == kb || bj == kb) return;
    __shared__ float R[64][65], Cl[64][65];
    int t = threadIdx.x;
    for (int e = 0; e < 16; e++) { int idx = t + e * 256; int r = idx >> 6, c = idx & 63;
        R[r][c]  = D[(size_t)(bi * 64 + r) * N + kb * 64 + c];
        Cl[r][c] = D[(size_t)(kb * 64 + r) * N + bj * 64 + c]; }
    __syncthreads();
    int r0 = (t >> 4) * 4, c0 = (t & 15) * 4;
    float acc[4][4];
    for (int e = 0; e < 4; e++) for (int f = 0; f < 4; f++) acc[e][f] = 3.4e38f;
    for (int k = 0; k < 64; k++) {
        float a[4], b[4];
        for (int e = 0; e < 4; e++) a[e] = R[r0 + e][k];
        for (int f = 0; f < 4; f++) b[f] = Cl[k][c0 + f];
        for (int e = 0; e < 4; e++)
            for (int f = 0; f < 4; f++) acc[e][f] = fminf(acc[e][f], a[e] + b[f]);
    }
    for (int e = 0; e < 4; e++)
        for (int f = 0; f < 4; f++) {
            size_t off = (size_t)(bi * 64 + r0 + e) * N + bj * 64 + c0 + f;
            D[off] = fminf(D[off], acc[e][f]);
        }
}

// ---------------- double centering ----------------
__global__ void k_rowmean(const float* __restrict__ D, double* __restrict__ rm) {
    int i = blockIdx.x, t = threadIdx.x;
    const float* dr = D + (size_t)i * N;
    double s = 0;
    for (int j = t; j < N; j += 256) { double d = (double)dr[j]; s += d * d; }
    __shared__ double red[256];
    red[t] = s; __syncthreads();
    for (int off = 128; off; off >>= 1) { if (t < off) red[t] += red[t + off]; __syncthreads(); }
    if (t == 0) rm[i] = red[0] / (double)N;
}

__global__ void k_grand(const double* __restrict__ rm, double* __restrict__ gm) {
    int t = threadIdx.x;
    double s = 0;
    for (int i = t; i < N; i += 256) s += rm[i];
    __shared__ double red[256];
    red[t] = s; __syncthreads();
    for (int off = 128; off; off >>= 1) { if (t < off) red[t] += red[t + off]; __syncthreads(); }
    if (t == 0) gm[0] = red[0] / (double)N;
}

__global__ void k_buildB(const float* __restrict__ D, const double* __restrict__ rm,
                         const double* __restrict__ gm, double* __restrict__ A) {
    int idx = blockIdx.x * 256 + threadIdx.x;
    int i = idx >> 11, j = idx & 2047;
    double d = (double)D[idx];
    A[idx] = -0.5 * (d * d - rm[i] - rm[j] + gm[0]);
}

__global__ void k_setV(float* __restrict__ V) {
    int idx = blockIdx.x * 256 + threadIdx.x;
    int i = idx >> 11, j = idx & 2047;
    V[idx] = (i == j) ? 1.f : 0.f;
}

// ---------------- Jacobi control ----------------
__global__ void k_initflags(unsigned* flags) { flags[0] = 0u; flags[1] = 0u; flags[2] = 0u; }
// once per sweep: convergence check on previous sweep's accumulated maxima, then reset
__global__ void k_sweepctl(unsigned* flags) {
    if (!flags[2]) {
        float mo = __uint_as_float(flags[0]), md = __uint_as_float(flags[1]);
        if (md > 0.f && mo <= 2e-9f * md) { flags[2] = 1u; return; }
        flags[0] = 0u; flags[1] = 0u;
    }
}

// ---- V <- V*Q for one 64-row stripe; shared by k_localv / k_vdrain ----
__device__ __forceinline__ void vapply_task(float* __restrict__ V, const double* __restrict__ qbP,
                                            const int* __restrict__ qp, int rnd, int task, int t) {
    int p = task >> 5, rt = task & 31;
    if (!qp[p]) return;
    __shared__ float Qs[32][33], Tv[64][33];
    int bi, bj; rr_pairN(rnd, p, NB, bi, bj);
    for (int e = 0; e < 4; e++) {
        int idx = t + e * 256; int a = idx >> 5, c = idx & 31;
        Qs[a][c] = (float)qbP[(size_t)p * 1024 + idx];
    }
    for (int e = 0; e < 8; e++) {
        int idx = t + e * 256; int a = idx >> 5, c = idx & 31;
        int gc = (c < 16) ? bi * 16 + c : bj * 16 + (c - 16);
        Tv[a][c] = V[(size_t)(rt * 64 + a) * N + gc];
    }
    __syncthreads();
    int r0 = (t >> 4) * 4, c0 = (t & 15) * 2;
    float acc[4][2] = {};
    for (int y = 0; y < 32; y++) {
        float q0 = Qs[y][c0], q1 = Qs[y][c0 + 1];
        for (int e = 0; e < 4; e++) {
            float vv = Tv[r0 + e][y];
            acc[e][0] += vv * q0; acc[e][1] += vv * q1;
        }
    }
    for (int e = 0; e < 4; e++)
        for (int f = 0; f < 2; f++) {
            int x = c0 + f;
            int gc = (x < 16) ? bi * 16 + x : bj * 16 + (x - 16);
            V[(size_t)(rt * 64 + r0 + e) * N + gc] = acc[e][f];
        }
}

// ---------------- local 32x32 Jacobi (blocks 0..63) || V-apply of pending round ----------------
// No inter-role dependency: local(r) touches A + qb/qfl[par]; V-apply(r-1) touches V + qb/qfl[pendP].
__global__ void __launch_bounds__(256) k_localv(double* __restrict__ A, float* __restrict__ V,
                                                double* __restrict__ qb,
                                                int* __restrict__ qfl, unsigned* __restrict__ flags,
                                                int round, int par, int pendR, int pendP) {
    int t = threadIdx.x;
    if (blockIdx.x >= NPAIRS) {
        if (pendR < 0) return;
        vapply_task(V, qb + (size_t)pendP * (NPAIRS * 1024), qfl + pendP * NPAIRS,
                    pendR, (int)blockIdx.x - NPAIRS, t);
        return;
    }
    int p = blockIdx.x;
    double* qbC = qb + (size_t)par * (NPAIRS * 1024);
    int* qflC = qfl + par * NPAIRS;
    if (flags[2]) { if (t == 0) qflC[p] = 0; return; }
    __shared__ double M[32][33], Q[32][33];
    __shared__ double cA[16], sA[16];
    __shared__ int ppA[16], qqA[16];
    __shared__ float red1[256], red2[256];
    __shared__ int everr;
    int bi, bj; rr_pairN(round, p, NB, bi, bj);

    // canonical sub-block load of the 32x32 pair tile + max scan on loaded values
    int rr = t >> 4, cc = t & 15;
    int tm[2] = { bi, bj };
    float offm = 0.f, diagm = 0.f;
    for (int s = 0; s < 4; s++) {
        int u = tm[s >> 1], v = tm[s & 1];
        double val; int dr, dc;
        if (u <= v) { val = A[(size_t)(u * 16 + rr) * N + v * 16 + cc]; dr = (s >> 1) * 16 + rr; dc = (s & 1) * 16 + cc; }
        else        { val = A[(size_t)(v * 16 + rr) * N + u * 16 + cc]; dr = (s >> 1) * 16 + cc; dc = (s & 1) * 16 + rr; }
        M[dr][dc] = val;
        float av = (float)fabs(val);
        if ((s == 0 || s == 3)) { if (rr == cc) diagm = fmaxf(diagm, av); else offm = fmaxf(offm, av); }
        else offm = fmaxf(offm, av);
    }
    for (int e = 0; e < 4; e++) {
        int idx = t + e * 256; int x = idx >> 5, y = idx & 31;
        Q[x][y] = (x == y) ? 1.0 : 0.0;
    }
    red1[t] = offm; red2[t] = diagm;
    if (t == 0) everr = 0;
    __syncthreads();
    for (int off = 128; off; off >>= 1) {
        if (t < off) { red1[t] = fmaxf(red1[t], red1[t + off]); red2[t] = fmaxf(red2[t], red2[t + off]); }
        __syncthreads();
    }
    float dmaxf = red2[0], off0 = red1[0];
    if (t == 0) { atomicMax(flags + 0, __float_as_uint(off0)); atomicMax(flags + 1, __float_as_uint(dmaxf)); }
    double dmax = (double)dmaxf;
    if ((double)off0 <= 1e-9 * dmax) { if (t == 0) qflC[p] = 0; return; }
    double thr = fmax(1e-13 * dmax, 1e-5 * (double)off0);

    for (int ir = 0; ir < 31; ir++) {
        if (t < 16) {
            int pp, qq; rr_pairN(ir, t, 32, pp, qq);
            double app = M[pp][pp], aqq = M[qq][qq], apq = M[pp][qq];
            double c = 1.0, sn = 0.0;
            if (fabs(apq) > thr) {
                double tau = (aqq - app) / (2.0 * apq);
                double tt2 = ((tau >= 0.0) ? 1.0 : -1.0) / (fabs(tau) + sqrt(1.0 + tau * tau));
                c = 1.0 / sqrt(1.0 + tt2 * tt2);
                sn = tt2 * c;
                everr = 1;
            }
            ppA[t] = pp; qqA[t] = qq; cA[t] = c; sA[t] = sn;
        }
        __syncthreads();
        // col updates: M <- M*J, Q <- Q*J  (512 slots, 2/thread)
        for (int e = 0; e < 2; e++) {
            int slot = t + e * 256; int mm = slot >> 5, k = slot & 31;
            double sn = sA[mm];
            if (sn != 0.0) {
                int pp = ppA[mm], qq = qqA[mm]; double c = cA[mm];
                double a = M[k][pp], b = M[k][qq];
                M[k][pp] = c * a - sn * b; M[k][qq] = sn * a + c * b;
                a = Q[k][pp]; b = Q[k][qq];
                Q[k][pp] = c * a - sn * b; Q[k][qq] = sn * a + c * b;
            }
        }
        __syncthreads();
        // row updates: M <- J^T * M
        for (int e = 0; e < 2; e++) {
            int slot = t + e * 256; int mm = slot >> 5, k = slot & 31;
            double sn = sA[mm];
            if (sn != 0.0) {
                int pp = ppA[mm], qq = qqA[mm]; double c = cA[mm];
                double a = M[pp][k], b = M[qq][k];
                M[pp][k] = c * a - sn * b; M[qq][k] = sn * a + c * b;
            }
        }
        __syncthreads();
    }
    int ev = everr;
    if (t == 0) qflC[p] = ev;
    if (ev) {
        for (int e = 0; e < 4; e++) {
            int idx = t + e * 256; int x = idx >> 5, y = idx & 31;
            qbC[(size_t)p * 1024 + idx] = Q[x][y];
        }
        // canonical write-back: (bi,bi), (bj,bj), and the canonical off-diag block
        A[(size_t)(bi * 16 + rr) * N + bi * 16 + cc] = M[rr][cc];
        A[(size_t)(bj * 16 + rr) * N + bj * 16 + cc] = M[16 + rr][16 + cc];
        if (bi <= bj) A[(size_t)(bi * 16 + rr) * N + bj * 16 + cc] = M[rr][16 + cc];
        else          A[(size_t)(bj * 16 + rr) * N + bi * 16 + cc] = M[16 + rr][cc];
    }
}

// ---------------- tri-apply: A <- Qr^T A Qc on upper-tri pair tiles (fp64 MFMA) ----------------
// One wave per 16x16 output quadrant; K=32 in 8 MFMA(16x16x4) steps.
// Canonical A storage: loads/stores go through per-sub-block transpose handling.
__global__ void __launch_bounds__(256) k_tri(double* __restrict__ A,
                                             const double* __restrict__ qb,
                                             const int* __restrict__ qfl,
                                             const unsigned* __restrict__ flags,
                                             int round, int par) {
    if (flags[2]) return;
    const double* qbC = qb + (size_t)par * (NPAIRS * 1024);
    const int* qflC = qfl + par * NPAIRS;
    int t = threadIdx.x;
    int task = blockIdx.x;
    int pr = 0, rem = task;
    while (rem >= 63 - pr) { rem -= 63 - pr; pr++; }
    int pc = pr + 1 + rem;
    int fr = qflC[pr], fc = qflC[pc];
    if (!fr && !fc) return;
    __shared__ double T[32][33], Qb[32][33];
    int bir, bjr, bic, bjc;
    rr_pairN(round, pr, NB, bir, bjr);
    rr_pairN(round, pc, NB, bic, bjc);
    int rt[2] = { bir, bjr }, ct[2] = { bic, bjc };
    int rr = t >> 4, cc = t & 15;
    if (fr) {
        for (int e = 0; e < 4; e++) {
            int idx = t + e * 256; int a = idx >> 5, b = idx & 31;
            Qb[a][b] = qbC[(size_t)pr * 1024 + idx];
        }
    }
    for (int s = 0; s < 4; s++) {
        int u = rt[s >> 1], v = ct[s & 1];
        if (u <= v) T[(s >> 1) * 16 + rr][(s & 1) * 16 + cc] = A[(size_t)(u * 16 + rr) * N + v * 16 + cc];
        else        T[(s >> 1) * 16 + cc][(s & 1) * 16 + rr] = A[(size_t)(v * 16 + rr) * N + u * 16 + cc];
    }
    __syncthreads();
    int wv = t >> 6, ln = t & 63;
    int i0 = (wv >> 1) * 16, j0 = (wv & 1) * 16;   // this wave's 16x16 output quadrant
    int li = ln & 15, lk = ln >> 4;
    if (fr) {
        // C1 = Qr^T * T : A_mat[i][y] = Qr[y][i], B_mat[y][j] = T[y][j]
        d4_t d = {0.0, 0.0, 0.0, 0.0};
        #pragma unroll
        for (int y0 = 0; y0 < 32; y0 += 4) {
            double a = Qb[y0 + lk][i0 + li];
            double b = T[y0 + lk][j0 + li];
            d = __builtin_amdgcn_mfma_f64_16x16x4f64(a, b, d, 0, 0, 0);
        }
        __syncthreads();
        #pragma unroll
        for (int v = 0; v < 4; v++) T[i0 + lk * 4 + v][j0 + li] = d[v];
        __syncthreads();
    }
    if (fc) {
        for (int e = 0; e < 4; e++) {
            int idx = t + e * 256; int a = idx >> 5, b = idx & 31;
            Qb[a][b] = qbC[(size_t)pc * 1024 + idx];
        }
        __syncthreads();
        // C2 = T * Qc : A_mat[i][y] = T[i][y], B_mat[y][j] = Qc[y][j]
        d4_t d = {0.0, 0.0, 0.0, 0.0};
        #pragma unroll
        for (int y0 = 0; y0 < 32; y0 += 4) {
            double a = T[i0 + li][y0 + lk];
            double b = Qb[y0 + lk][j0 + li];
            d = __builtin_amdgcn_mfma_f64_16x16x4f64(a, b, d, 0, 0, 0);
        }
        __syncthreads();
        #pragma unroll
        for (int v = 0; v < 4; v++) T[i0 + lk * 4 + v][j0 + li] = d[v];
        __syncthreads();
    }
    // canonical store: each of the 4 sub-blocks written once at its canonical home
    for (int s = 0; s < 4; s++) {
        int u = rt[s >> 1], v = ct[s & 1];
        if (u <= v) A[(size_t)(u * 16 + rr) * N + v * 16 + cc] = T[(s >> 1) * 16 + rr][(s & 1) * 16 + cc];
        else        A[(size_t)(v * 16 + rr) * N + u * 16 + cc] = T[(s >> 1) * 16 + cc][(s & 1) * 16 + rr];
    }
}

// drain: V-apply of the final round
__global__ void __launch_bounds__(256) k_vdrain(float* __restrict__ V, const double* __restrict__ qb,
                                                const int* __restrict__ qfl, int rnd, int par) {
    vapply_task(V, qb + (size_t)par * (NPAIRS * 1024), qfl + par * NPAIRS,
                rnd, (int)blockIdx.x, threadIdx.x);
}

// ---------------- epilogue ----------------
__global__ void k_lambda(const double* __restrict__ A, double* __restrict__ lam) {
    int i = blockIdx.x * 256 + threadIdx.x;
    if (i < N) lam[i] = A[(size_t)i * N + i];
}

__global__ void __launch_bounds__(1024) k_sort(const double* __restrict__ lam,
                                               double* __restrict__ lams, int* __restrict__ order) {
    __shared__ double v[2048]; __shared__ int ix[2048];
    int t = threadIdx.x;
    v[t] = lam[t]; v[t + 1024] = lam[t + 1024];
    ix[t] = t; ix[t + 1024] = t + 1024;
    __syncthreads();
    for (int k = 2; k <= 2048; k <<= 1) {
        for (int j = k >> 1; j > 0; j >>= 1) {
            int l = ((t & ~(j - 1)) << 1) | (t & (j - 1));
            int partner = l | j;
            double va = v[l], vb = v[partner]; int ia = ix[l], ib = ix[partner];
            bool before = (va > vb) || (va == vb && ia < ib);
            bool asc = ((l & k) == 0);
            bool doSwap = asc ? (!before) : before;
            if (doSwap) { v[l] = vb; v[partner] = va; ix[l] = ib; ix[partner] = ia; }
            __syncthreads();
        }
    }
    lams[t] = v[t]; lams[t + 1024] = v[t + 1024];
    order[t] = ix[t]; order[t + 1024] = ix[t + 1024];
}

__global__ void k_out(const float* __restrict__ Vm, const double* __restrict__ lams,
                      const int* __restrict__ order, float* __restrict__ out) {
    int c = blockIdx.x, t = threadIdx.x;
    int col = order[c];
    __shared__ float rv[256]; __shared__ int ri[256];
    float bv = -1.f; int bidx = N;
    for (int i = t; i < N; i += 256) {
        float av = fabsf(Vm[(size_t)i * N + col]);
        if (av > bv || (av == bv && i < bidx)) { bv = av; bidx = i; }
    }
    rv[t] = bv; ri[t] = bidx;
    __syncthreads();
    for (int off = 128; off; off >>= 1) {
        if (t < off) {
            if (rv[t + off] > rv[t] || (rv[t + off] == rv[t] && ri[t + off] < ri[t])) {
                rv[t] = rv[t + off]; ri[t] = ri[t + off];
            }
        }
        __syncthreads();
    }
    float sv = Vm[(size_t)ri[0] * N + col];
    float s = (sv > 0.f) ? 1.f : ((sv < 0.f) ? -1.f : 0.f);
    double lv = lams[c];
    float f = s * (float)sqrt(lv > 0.0 ? lv : 0.0);
    for (int i = t; i < N; i += 256) out[(size_t)i * NC + c] = Vm[(size_t)i * N + col] * f;
}

extern "C" void kernel_launch(void* const* d_in, const int* in_sizes, int n_in,
                              void* d_out, int out_size, void* d_ws, size_t ws_size,
                              hipStream_t stream) {
    (void)in_sizes; (void)n_in; (void)out_size; (void)ws_size;
    const float* X = (const float*)d_in[0];
    float* out = (float*)d_out;

    double* rm  = (double*)d_ws;                 // N
    double* gm  = rm + N;                        // 1 (+7 pad)
    double* lam = gm + 8;                        // N
    double* lams= lam + N;                       // N
    double* A   = lams + N;                      // N*N fp64
    double* qb  = A + (size_t)N * N;             // 2 * NPAIRS*1024 fp64 (double-buffered)
    float* Dg   = (float*)(qb + 2 * (size_t)NPAIRS * 1024); // N*N f32
    float* Vm   = Dg + (size_t)N * N;            // N*N f32
    float* sq   = Vm + (size_t)N * N;            // N
    int* order  = (int*)(sq + N);                // N
    int* qfl    = order + N;                     // 2 * NPAIRS
    unsigned* flags = (unsigned*)(qfl + 2 * NPAIRS); // 3
    float* dist = (float*)A;                     // alias: dist dies before A is born

    // 1. pairwise distances
    k_rowsq<<<N / 4, 256, 0, stream>>>(X, sq);
    k_dist<<<dim3(32, 32), 256, 0, stream>>>(X, sq, dist);

    // 2. KNN graph
    k_knn<<<N, 256, 0, stream>>>(dist, Dg);
    k_symdiag<<<(N * N) / 256, 256, 0, stream>>>(Dg);

    // 3. blocked Floyd-Warshall
    for (int kb = 0; kb < N / 64; kb++) {
        k_fw12<<<63, 256, 0, stream>>>(Dg, kb);
        k_fw3<<<dim3(32, 32), 256, 0, stream>>>(Dg, kb);
    }

    // 4. double centering -> B (fp64)
    k_rowmean<<<N, 256, 0, stream>>>(Dg, rm);
    k_grand<<<1, 256, 0, stream>>>(rm, gm);
    k_buildB<<<(N * N) / 256, 256, 0, stream>>>(Dg, rm, gm, A);
    k_setV<<<(N * N) / 256, 256, 0, stream>>>(Vm);
    k_initflags<<<1, 1, 0, stream>>>(flags);

    // 5. two-sided block Jacobi; V-apply of round g-1 overlaps local of round g
    int g = 0;
    for (int sw = 0; sw < NSWEEPS; sw++) {
        k_sweepctl<<<1, 1, 0, stream>>>(flags);
        for (int r = 0; r < NB - 1; r++, g++) {
            int par = g & 1;
            int pendR = (g == 0) ? -1 : ((g - 1) % (NB - 1));
            int pendP = (g - 1) & 1;
            k_localv<<<NPAIRS + NVS, 256, 0, stream>>>(A, Vm, qb, qfl, flags, r, par, pendR, pendP);
            k_tri<<<NTRI, 256, 0, stream>>>(A, qb, qfl, flags, r, par);
        }
    }
    // drain last round's V-apply
    {
        int glast = NSWEEPS * (NB - 1) - 1;
        k_vdrain<<<NVS, 256, 0, stream>>>(Vm, qb, qfl, glast % (NB - 1), glast & 1);
    }

    // 6. sort eigenvalues, sign-fix, scale, write output
    k_lambda<<<N / 256, 256, 0, stream>>>(A, lam);
    k_sort<<<1, 1024, 0, stream>>>(lam, lams, order);
    k_out<<<NC, 256, 0, stream>>>(Vm, lams, order, out);
}

// Round 6
// 72611.438 us; speedup vs baseline: 3.6268x; 1.1066x over previous
//
#include <hip/hip_runtime.h>
#include <math.h>

#define N 2048
#define DIMS 784
#define BIGV 1.0e6f
#define NC 784

// two-sided block Jacobi config: 128 teams of width 16, 32x32 local tiles
#define NB 128
#define NPAIRS 64
#define NSWEEPS 18
#define NTRI 2016      // 64*63/2 upper-tri pair tiles
#define NVS  2048      // 64 pairs * 32 V row-stripes

typedef __attribute__((ext_vector_type(4))) double d4_t;

// round-robin pairing over nteams: round r in [0,nteams-1), pair m in [0,nteams/2)
__device__ __forceinline__ void rr_pairN(int r, int m, int nteams, int& bi, int& bj) {
    int n1 = nteams - 1;
    if (m == 0) { bi = n1; bj = r % n1; }
    else { bi = (r + m) % n1; bj = (r - m + n1) % n1; }
}

// pair index of team x in round r (NB teams)
__device__ __forceinline__ int rr_pidx(int r, int x) {
    const int n1 = NB - 1;
    if (x == n1) return 0;
    int m = (x - r) % n1; if (m < 0) m += n1;
    if (m == 0) return 0;
    return (m <= n1 / 2) ? m : n1 - m;
}
// partner team of x in round r
__device__ __forceinline__ int rr_partner(int r, int x) {
    const int n1 = NB - 1;
    if (x == n1) return r % n1;
    int m = (x - r) % n1; if (m < 0) m += n1;
    if (m == 0) return n1;
    if (m <= n1 / 2) return (r - m + n1) % n1;
    int m2 = n1 - m; return (r + m2) % n1;
}

// A is stored CANONICALLY: 16x16 team-sub-block (u,v) valid only at u<=v.

// ---------------- distances ----------------
__global__ void k_rowsq(const float* __restrict__ X, float* __restrict__ sq) {
    int wave = threadIdx.x >> 6, lane = threadIdx.x & 63;
    int row = blockIdx.x * 4 + wave;
    const float* xr = X + (size_t)row * DIMS;
    float s = 0.f;
    for (int k = lane; k < DIMS; k += 64) { float v = xr[k]; s += v * v; }
    for (int off = 32; off; off >>= 1) s += __shfl_down(s, off);
    if (lane == 0) sq[row] = s;
}

__global__ void __launch_bounds__(256) k_dist(const float* __restrict__ X,
                                              const float* __restrict__ sq,
                                              float* __restrict__ out) {
    __shared__ float As[64][17], Bs[64][17];
    int ti = blockIdx.y, tj = blockIdx.x, t = threadIdx.x;
    int tx = t & 15, ty = t >> 4;
    float acc[4][4] = {};
    for (int k0 = 0; k0 < DIMS; k0 += 16) {
        for (int e = 0; e < 4; e++) {
            int idx = t + e * 256; int r = idx >> 4, c = idx & 15;
            As[r][c] = X[(size_t)(ti * 64 + r) * DIMS + k0 + c];
            Bs[r][c] = X[(size_t)(tj * 64 + r) * DIMS + k0 + c];
        }
        __syncthreads();
        for (int k = 0; k < 16; k++) {
            float a[4], b[4];
            for (int e = 0; e < 4; e++) a[e] = As[ty * 4 + e][k];
            for (int f = 0; f < 4; f++) b[f] = Bs[tx * 4 + f][k];
            for (int e = 0; e < 4; e++)
                for (int f = 0; f < 4; f++) acc[e][f] += a[e] * b[f];
        }
        __syncthreads();
    }
    for (int e = 0; e < 4; e++)
        for (int f = 0; f < 4; f++) {
            int gi = ti * 64 + ty * 4 + e, gj = tj * 64 + tx * 4 + f;
            float d2 = sq[gi] + sq[gj] - 2.f * acc[e][f];
            out[(size_t)gi * N + gj] = sqrtf(fmaxf(d2, 0.f));
        }
}

// ---------------- KNN graph ----------------
__global__ void k_knn(const float* __restrict__ dist, float* __restrict__ G) {
    int i = blockIdx.x, t = threadIdx.x;
    float bv[6]; int bidx[6];
    for (int k = 0; k < 6; k++) { bv[k] = 3.4e38f; bidx[k] = N; }
    const float* dr = dist + (size_t)i * N;
    for (int j = t; j < N; j += 256) {
        float v = dr[j];
        bool ins = (v < bv[5]) || (v == bv[5] && j < bidx[5]);
        if (ins) {
            int k = 5;
            while (k > 0) {
                bool mv = (v < bv[k - 1]) || (v == bv[k - 1] && j < bidx[k - 1]);
                if (!mv) break;
                bv[k] = bv[k - 1]; bidx[k] = bidx[k - 1]; k--;
            }
            bv[k] = v; bidx[k] = j;
        }
    }
    __shared__ float lv[256][6]; __shared__ int li[256][6];
    for (int k = 0; k < 6; k++) { lv[t][k] = bv[k]; li[t][k] = bidx[k]; }
    __syncthreads();
    for (int off = 128; off >= 1; off >>= 1) {
        if (t < off) {
            float av[6], cv[6]; int ai[6], ci[6];
            for (int k = 0; k < 6; k++) { av[k] = lv[t][k]; ai[k] = li[t][k]; cv[k] = lv[t + off][k]; ci[k] = li[t + off][k]; }
            float mv[6]; int mi[6]; int pa = 0, pb = 0;
            for (int k = 0; k < 6; k++) {
                bool ta;
                if (pa >= 6) ta = false;
                else if (pb >= 6) ta = true;
                else ta = (av[pa] < cv[pb]) || (av[pa] == cv[pb] && ai[pa] < ci[pb]);
                if (ta) { mv[k] = av[pa]; mi[k] = ai[pa]; pa++; }
                else    { mv[k] = cv[pb]; mi[k] = ci[pb]; pb++; }
            }
            for (int k = 0; k < 6; k++) { lv[t][k] = mv[k]; li[t][k] = mi[k]; }
        }
        __syncthreads();
    }
    float sv[6]; int si[6];
    for (int k = 0; k < 6; k++) { sv[k] = lv[0][k]; si[k] = li[0][k]; }
    for (int j = t; j < N; j += 256) {
        float val = BIGV;
        for (int k = 0; k < 6; k++) if (j == si[k]) val = sv[k];
        G[(size_t)i * N + j] = val;
    }
}

__global__ void k_symdiag(float* __restrict__ G) {
    int idx = blockIdx.x * 256 + threadIdx.x;
    int i = idx >> 11, j = idx & 2047;
    if (i == j) { G[idx] = 0.f; return; }
    if (j > i) {
        float a = G[(size_t)i * N + j], b = G[(size_t)j * N + i];
        float m = fminf(a, b);
        G[(size_t)i * N + j] = m; G[(size_t)j * N + i] = m;
    }
}

// ---------------- blocked Floyd-Warshall ----------------
__global__ void __launch_bounds__(256) k_fw12(float* __restrict__ D, int kb) {
    __shared__ float KK[64][65], C[64][65];
    int bx = blockIdx.x, t = threadIdx.x;
    for (int e = 0; e < 16; e++) { int idx = t + e * 256; int r = idx >> 6, c = idx & 63;
        KK[r][c] = D[(size_t)(kb * 64 + r) * N + kb * 64 + c]; }
    __syncthreads();
    int r0 = t >> 2, c0 = (t & 3) * 16;
    for (int k = 0; k < 64; k++) {
        float dk = KK[r0][k];
        for (int c = 0; c < 16; c++) KK[r0][c0 + c] = fminf(KK[r0][c0 + c], dk + KK[k][c0 + c]);
        __syncthreads();
    }
    if (bx == 62) {
        for (int e = 0; e < 16; e++) { int idx = t + e * 256; int r = idx >> 6, c = idx & 63;
            D[(size_t)(kb * 64 + r) * N + kb * 64 + c] = KK[r][c]; }
        return;
    }
    bool rowstripe = bx < 31;
    int o = rowstripe ? bx : bx - 31;
    o += (o >= kb) ? 1 : 0;
    int baseR = rowstripe ? kb : o;
    int baseC = rowstripe ? o : kb;
    for (int e = 0; e < 16; e++) { int idx = t + e * 256; int r = idx >> 6, c = idx & 63;
        C[r][c] = D[(size_t)(baseR * 64 + r) * N + baseC * 64 + c]; }
    __syncthreads();
    if (rowstripe) {
        for (int k = 0; k < 64; k++) {
            float dk = KK[r0][k];
            for (int c = 0; c < 16; c++) C[r0][c0 + c] = fminf(C[r0][c0 + c], dk + C[k][c0 + c]);
            __syncthreads();
        }
    } else {
        for (int k = 0; k < 64; k++) {
            float dk = C[r0][k];
            for (int c = 0; c < 16; c++) C[r0][c0 + c] = fminf(C[r0][c0 + c], dk + KK[k][c0 + c]);
            __syncthreads();
        }
    }
    for (int e = 0; e < 16; e++) { int idx = t + e * 256; int r = idx >> 6, c = idx & 63;
        D[(size_t)(baseR * 64 + r) * N + baseC * 64 + c] = C[r][c]; }
}

__global__ void __launch_bounds__(256) k_fw3(float* __restrict__ D, int kb) {
    int bi = blockIdx.y, bj = blockIdx.x;
    if (bi == kb || bj == kb) return;
    __shared__ float R[64][65], Cl[64][65];
    int t = threadIdx.x;
    for (int e = 0; e < 16; e++) { int idx = t + e * 256; int r = idx >> 6, c = idx & 63;
        R[r][c]  = D[(size_t)(bi * 64 + r) * N + kb * 64 + c];
        Cl[r][c] = D[(size_t)(kb * 64 + r) * N + bj * 64 + c]; }
    __syncthreads();
    int r0 = (t >> 4) * 4, c0 = (t & 15) * 4;
    float acc[4][4];
    for (int e = 0; e < 4; e++) for (int f = 0; f < 4; f++) acc[e][f] = 3.4e38f;
    for (int k = 0; k < 64; k++) {
        float a[4], b[4];
        for (int e = 0; e < 4; e++) a[e] = R[r0 + e][k];
        for (int f = 0; f < 4; f++) b[f] = Cl[k][c0 + f];
        for (int e = 0; e < 4; e++)
            for (int f = 0; f < 4; f++) acc[e][f] = fminf(acc[e][f], a[e] + b[f]);
    }
    for (int e = 0; e < 4; e++)
        for (int f = 0; f < 4; f++) {
            size_t off = (size_t)(bi * 64 + r0 + e) * N + bj * 64 + c0 + f;
            D[off] = fminf(D[off], acc[e][f]);
        }
}

// ---------------- double centering ----------------
__global__ void k_rowmean(const float* __restrict__ D, double* __restrict__ rm) {
    int i = blockIdx.x, t = threadIdx.x;
    const float* dr = D + (size_t)i * N;
    double s = 0;
    for (int j = t; j < N; j += 256) { double d = (double)dr[j]; s += d * d; }
    __shared__ double red[256];
    red[t] = s; __syncthreads();
    for (int off = 128; off; off >>= 1) { if (t < off) red[t] += red[t + off]; __syncthreads(); }
    if (t == 0) rm[i] = red[0] / (double)N;
}

__global__ void k_grand(const double* __restrict__ rm, double* __restrict__ gm) {
    int t = threadIdx.x;
    double s = 0;
    for (int i = t; i < N; i += 256) s += rm[i];
    __shared__ double red[256];
    red[t] = s; __syncthreads();
    for (int off = 128; off; off >>= 1) { if (t < off) red[t] += red[t + off]; __syncthreads(); }
    if (t == 0) gm[0] = red[0] / (double)N;
}

__global__ void k_buildB(const float* __restrict__ D, const double* __restrict__ rm,
                         const double* __restrict__ gm, double* __restrict__ A) {
    int idx = blockIdx.x * 256 + threadIdx.x;
    int i = idx >> 11, j = idx & 2047;
    double d = (double)D[idx];
    A[idx] = -0.5 * (d * d - rm[i] - rm[j] + gm[0]);
}

__global__ void k_setV(float* __restrict__ V) {
    int idx = blockIdx.x * 256 + threadIdx.x;
    int i = idx >> 11, j = idx & 2047;
    V[idx] = (i == j) ? 1.f : 0.f;
}

// ---------------- Jacobi control ----------------
__global__ void k_initflags(unsigned* flags) { flags[0] = 0u; flags[1] = 0u; flags[2] = 0u; }
__global__ void k_sweepctl(unsigned* flags) {
    if (!flags[2]) {
        float mo = __uint_as_float(flags[0]), md = __uint_as_float(flags[1]);
        if (md > 0.f && mo <= 2e-9f * md) { flags[2] = 1u; return; }
        flags[0] = 0u; flags[1] = 0u;
    }
}

// ---------------- task bodies (shared-union via smem base pointer) ----------------
// smem: double[2432] = 19456 B per block.

// V <- V*Q for one 64-row stripe
__device__ __forceinline__ void vapply_task(float* __restrict__ V, const double* __restrict__ qbP,
                                            const int* __restrict__ qp, int rnd, int task, int t,
                                            double* smem) {
    int p = task >> 5, rt = task & 31;
    if (!qp[p]) return;
    float (*Qs)[33] = (float(*)[33])smem;
    float (*Tv)[33] = (float(*)[33])(smem + 528);
    int bi, bj; rr_pairN(rnd, p, NB, bi, bj);
    for (int e = 0; e < 4; e++) {
        int idx = t + e * 256; int a = idx >> 5, c = idx & 31;
        Qs[a][c] = (float)qbP[(size_t)p * 1024 + idx];
    }
    for (int e = 0; e < 8; e++) {
        int idx = t + e * 256; int a = idx >> 5, c = idx & 31;
        int gc = (c < 16) ? bi * 16 + c : bj * 16 + (c - 16);
        Tv[a][c] = V[(size_t)(rt * 64 + a) * N + gc];
    }
    __syncthreads();
    int r0 = (t >> 4) * 4, c0 = (t & 15) * 2;
    float acc[4][2] = {};
    for (int y = 0; y < 32; y++) {
        float q0 = Qs[y][c0], q1 = Qs[y][c0 + 1];
        for (int e = 0; e < 4; e++) {
            float vv = Tv[r0 + e][y];
            acc[e][0] += vv * q0; acc[e][1] += vv * q1;
        }
    }
    for (int e = 0; e < 4; e++)
        for (int f = 0; f < 2; f++) {
            int x = c0 + f;
            int gc = (x < 16) ? bi * 16 + x : bj * 16 + (x - 16);
            V[(size_t)(rt * 64 + r0 + e) * N + gc] = acc[e][f];
        }
}

// local 32x32 Jacobi on pair p of `round`
__device__ __forceinline__ void local_task(double* __restrict__ A, double* __restrict__ qb,
                                           int* __restrict__ qfl, unsigned* __restrict__ flags,
                                           int round, int par, int p, int t, double* smem) {
    double* qbC = qb + (size_t)par * (NPAIRS * 1024);
    int* qflC = qfl + par * NPAIRS;
    if (flags[2]) { if (t == 0) qflC[p] = 0; return; }
    double (*M)[33] = (double(*)[33])smem;
    double (*Q)[33] = (double(*)[33])(smem + 1056);
    double* cA = smem + 2112; double* sA = smem + 2128;
    int* ppA = (int*)(smem + 2144); int* qqA = ppA + 16;
    float* red1 = (float*)(smem + 2160);
    float* red2 = (float*)(smem + 2288);
    int* everr = (int*)(smem + 2416);
    int bi, bj; rr_pairN(round, p, NB, bi, bj);

    int rr = t >> 4, cc = t & 15;
    int tm[2] = { bi, bj };
    float offm = 0.f, diagm = 0.f;
    for (int s = 0; s < 4; s++) {
        int u = tm[s >> 1], v = tm[s & 1];
        double val; int dr, dc;
        if (u <= v) { val = A[(size_t)(u * 16 + rr) * N + v * 16 + cc]; dr = (s >> 1) * 16 + rr; dc = (s & 1) * 16 + cc; }
        else        { val = A[(size_t)(v * 16 + rr) * N + u * 16 + cc]; dr = (s >> 1) * 16 + cc; dc = (s & 1) * 16 + rr; }
        M[dr][dc] = val;
        float av = (float)fabs(val);
        if (s == 0 || s == 3) { if (rr == cc) diagm = fmaxf(diagm, av); else offm = fmaxf(offm, av); }
        else offm = fmaxf(offm, av);
    }
    for (int e = 0; e < 4; e++) {
        int idx = t + e * 256; int x = idx >> 5, y = idx & 31;
        Q[x][y] = (x == y) ? 1.0 : 0.0;
    }
    red1[t] = offm; red2[t] = diagm;
    if (t == 0) *everr = 0;
    __syncthreads();
    for (int off = 128; off; off >>= 1) {
        if (t < off) { red1[t] = fmaxf(red1[t], red1[t + off]); red2[t] = fmaxf(red2[t], red2[t + off]); }
        __syncthreads();
    }
    float dmaxf = red2[0], off0 = red1[0];
    if (t == 0) { atomicMax(flags + 0, __float_as_uint(off0)); atomicMax(flags + 1, __float_as_uint(dmaxf)); }
    double dmax = (double)dmaxf;
    if ((double)off0 <= 1e-9 * dmax) { if (t == 0) qflC[p] = 0; return; }
    double thr = fmax(1e-13 * dmax, 1e-5 * (double)off0);

    for (int ir = 0; ir < 31; ir++) {
        if (t < 16) {
            int pp, qq; rr_pairN(ir, t, 32, pp, qq);
            double app = M[pp][pp], aqq = M[qq][qq], apq = M[pp][qq];
            double c = 1.0, sn = 0.0;
            if (fabs(apq) > thr) {
                double tau = (aqq - app) / (2.0 * apq);
                double tt2 = ((tau >= 0.0) ? 1.0 : -1.0) / (fabs(tau) + sqrt(1.0 + tau * tau));
                c = 1.0 / sqrt(1.0 + tt2 * tt2);
                sn = tt2 * c;
                *everr = 1;
            }
            ppA[t] = pp; qqA[t] = qq; cA[t] = c; sA[t] = sn;
        }
        __syncthreads();
        for (int e = 0; e < 2; e++) {
            int slot = t + e * 256; int mm = slot >> 5, k = slot & 31;
            double sn = sA[mm];
            if (sn != 0.0) {
                int pp = ppA[mm], qq = qqA[mm]; double c = cA[mm];
                double a = M[k][pp], b = M[k][qq];
                M[k][pp] = c * a - sn * b; M[k][qq] = sn * a + c * b;
                a = Q[k][pp]; b = Q[k][qq];
                Q[k][pp] = c * a - sn * b; Q[k][qq] = sn * a + c * b;
            }
        }
        __syncthreads();
        for (int e = 0; e < 2; e++) {
            int slot = t + e * 256; int mm = slot >> 5, k = slot & 31;
            double sn = sA[mm];
            if (sn != 0.0) {
                int pp = ppA[mm], qq = qqA[mm]; double c = cA[mm];
                double a = M[pp][k], b = M[qq][k];
                M[pp][k] = c * a - sn * b; M[qq][k] = sn * a + c * b;
            }
        }
        __syncthreads();
    }
    int ev = *everr;
    if (t == 0) qflC[p] = ev;
    if (ev) {
        for (int e = 0; e < 4; e++) {
            int idx = t + e * 256; int x = idx >> 5, y = idx & 31;
            qbC[(size_t)p * 1024 + idx] = Q[x][y];
        }
        A[(size_t)(bi * 16 + rr) * N + bi * 16 + cc] = M[rr][cc];
        A[(size_t)(bj * 16 + rr) * N + bj * 16 + cc] = M[16 + rr][16 + cc];
        if (bi <= bj) A[(size_t)(bi * 16 + rr) * N + bj * 16 + cc] = M[rr][16 + cc];
        else          A[(size_t)(bj * 16 + rr) * N + bi * 16 + cc] = M[16 + rr][cc];
    }
}

// tri-apply: A <- Qr^T A Qc on pair tile (pr,pc), fp64 MFMA, canonical storage
__device__ __forceinline__ void tri_task(double* __restrict__ A, const double* __restrict__ qbC,
                                         const int* __restrict__ qflC, int round, int pr, int pc,
                                         int t, double* smem) {
    int fr = qflC[pr], fc = qflC[pc];
    if (!fr && !fc) return;
    double (*T)[33] = (double(*)[33])smem;
    double (*Qb)[33] = (double(*)[33])(smem + 1056);
    int bir, bjr, bic, bjc;
    rr_pairN(round, pr, NB, bir, bjr);
    rr_pairN(round, pc, NB, bic, bjc);
    int rt[2] = { bir, bjr }, ct[2] = { bic, bjc };
    int rr = t >> 4, cc = t & 15;
    if (fr) {
        for (int e = 0; e < 4; e++) {
            int idx = t + e * 256; int a = idx >> 5, b = idx & 31;
            Qb[a][b] = qbC[(size_t)pr * 1024 + idx];
        }
    }
    for (int s = 0; s < 4; s++) {
        int u = rt[s >> 1], v = ct[s & 1];
        if (u <= v) T[(s >> 1) * 16 + rr][(s & 1) * 16 + cc] = A[(size_t)(u * 16 + rr) * N + v * 16 + cc];
        else        T[(s >> 1) * 16 + cc][(s & 1) * 16 + rr] = A[(size_t)(v * 16 + rr) * N + u * 16 + cc];
    }
    __syncthreads();
    int wv = t >> 6, ln = t & 63;
    int i0 = (wv >> 1) * 16, j0 = (wv & 1) * 16;
    int li = ln & 15, lk = ln >> 4;
    if (fr) {
        d4_t d = {0.0, 0.0, 0.0, 0.0};
        #pragma unroll
        for (int y0 = 0; y0 < 32; y0 += 4) {
            double a = Qb[y0 + lk][i0 + li];
            double b = T[y0 + lk][j0 + li];
            d = __builtin_amdgcn_mfma_f64_16x16x4f64(a, b, d, 0, 0, 0);
        }
        __syncthreads();
        #pragma unroll
        for (int v = 0; v < 4; v++) T[i0 + lk * 4 + v][j0 + li] = d[v];
        __syncthreads();
    }
    if (fc) {
        for (int e = 0; e < 4; e++) {
            int idx = t + e * 256; int a = idx >> 5, b = idx & 31;
            Qb[a][b] = qbC[(size_t)pc * 1024 + idx];
        }
        __syncthreads();
        d4_t d = {0.0, 0.0, 0.0, 0.0};
        #pragma unroll
        for (int y0 = 0; y0 < 32; y0 += 4) {
            double a = T[i0 + li][y0 + lk];
            double b = Qb[y0 + lk][j0 + li];
            d = __builtin_amdgcn_mfma_f64_16x16x4f64(a, b, d, 0, 0, 0);
        }
        __syncthreads();
        #pragma unroll
        for (int v = 0; v < 4; v++) T[i0 + lk * 4 + v][j0 + li] = d[v];
        __syncthreads();
    }
    for (int s = 0; s < 4; s++) {
        int u = rt[s >> 1], v = ct[s & 1];
        if (u <= v) A[(size_t)(u * 16 + rr) * N + v * 16 + cc] = T[(s >> 1) * 16 + rr][(s & 1) * 16 + cc];
        else        A[(size_t)(v * 16 + rr) * N + u * 16 + cc] = T[(s >> 1) * 16 + cc][(s & 1) * 16 + rr];
    }
}

// ---------------- pipelined Jacobi kernels ----------------
// round 0 local, standalone prologue
__global__ void __launch_bounds__(256) k_local0(double* __restrict__ A, double* __restrict__ qb,
                                                int* __restrict__ qfl, unsigned* __restrict__ flags) {
    __shared__ double smem[2432];
    local_task(A, qb, qfl, flags, 0, 0, (int)blockIdx.x, (int)threadIdx.x, smem);
}

// critical tri tasks of `round`: those whose output blocks feed local(nextRound).
// One block per nextRound pair; ownership dedup (a task can serve 2 next-pairs).
__global__ void __launch_bounds__(256) k_trium(double* __restrict__ A, const double* __restrict__ qb,
                                               const int* __restrict__ qfl, const unsigned* __restrict__ flags,
                                               int round, int par, int nextRound) {
    if (flags[2]) return;
    int mp = blockIdx.x;
    int u, v; rr_pairN(nextRound, mp, NB, u, v);
    int a = rr_pidx(round, u), b = rr_pidx(round, v);
    int pr = min(a, b), pc = max(a, b);
    int bir, bjr, bic, bjc;
    rr_pairN(round, pr, NB, bir, bjr);
    rr_pairN(round, pc, NB, bic, bjc);
    int own = 1000;
    #pragma unroll
    for (int s = 0; s < 4; s++) {
        int tu = (s >> 1) ? bjr : bir, tv = (s & 1) ? bjc : bic;
        if (rr_partner(nextRound, tu) == tv) { int mm = rr_pidx(nextRound, tu); own = min(own, mm); }
    }
    if (own != mp) return;
    __shared__ double smem[2432];
    tri_task(A, qb + (size_t)par * (NPAIRS * 1024), qfl + par * NPAIRS, round, pr, pc,
             (int)threadIdx.x, smem);
}

// fused: local(nextRound) [blocks 0..63] || tri_rest(round) || V-apply(round)
__global__ void __launch_bounds__(256) k_fused(double* __restrict__ A, float* __restrict__ V,
                                               double* __restrict__ qb, int* __restrict__ qfl,
                                               unsigned* __restrict__ flags,
                                               int round, int par, int nextRound, int nextPar,
                                               int nextValid) {
    __shared__ double smem[2432];
    int t = threadIdx.x, blk = blockIdx.x;
    if (blk < NPAIRS) {
        if (!nextValid) return;
        local_task(A, qb, qfl, flags, nextRound, nextPar, blk, t, smem);
    } else if (blk < NPAIRS + NTRI) {
        if (flags[2]) return;
        int task = blk - NPAIRS;
        int pr = 0, rem = task;
        while (rem >= 63 - pr) { rem -= 63 - pr; pr++; }
        int pc = pr + 1 + rem;
        int bir, bjr, bic, bjc;
        rr_pairN(round, pr, NB, bir, bjr);
        rr_pairN(round, pc, NB, bic, bjc);
        #pragma unroll
        for (int s = 0; s < 4; s++) {
            int tu = (s >> 1) ? bjr : bir, tv = (s & 1) ? bjc : bic;
            if (rr_partner(nextRound, tu) == tv) return;   // critical: k_trium handled it
        }
        tri_task(A, qb + (size_t)par * (NPAIRS * 1024), qfl + par * NPAIRS, round, pr, pc, t, smem);
    } else {
        if (flags[2]) return;
        vapply_task(V, qb + (size_t)par * (NPAIRS * 1024), qfl + par * NPAIRS,
                    round, blk - NPAIRS - NTRI, t, smem);
    }
}

// ---------------- epilogue ----------------
__global__ void k_lambda(const double* __restrict__ A, double* __restrict__ lam) {
    int i = blockIdx.x * 256 + threadIdx.x;
    if (i < N) lam[i] = A[(size_t)i * N + i];
}

__global__ void __launch_bounds__(1024) k_sort(const double* __restrict__ lam,
                                               double* __restrict__ lams, int* __restrict__ order) {
    __shared__ double v[2048]; __shared__ int ix[2048];
    int t = threadIdx.x;
    v[t] = lam[t]; v[t + 1024] = lam[t + 1024];
    ix[t] = t; ix[t + 1024] = t + 1024;
    __syncthreads();
    for (int k = 2; k <= 2048; k <<= 1) {
        for (int j = k >> 1; j > 0; j >>= 1) {
            int l = ((t & ~(j - 1)) << 1) | (t & (j - 1));
            int partner = l | j;
            double va = v[l], vb = v[partner]; int ia = ix[l], ib = ix[partner];
            bool before = (va > vb) || (va == vb && ia < ib);
            bool asc = ((l & k) == 0);
            bool doSwap = asc ? (!before) : before;
            if (doSwap) { v[l] = vb; v[partner] = va; ix[l] = ib; ix[partner] = ia; }
            __syncthreads();
        }
    }
    lams[t] = v[t]; lams[t + 1024] = v[t + 1024];
    order[t] = ix[t]; order[t + 1024] = ix[t + 1024];
}

__global__ void k_out(const float* __restrict__ Vm, const double* __restrict__ lams,
                      const int* __restrict__ order, float* __restrict__ out) {
    int c = blockIdx.x, t = threadIdx.x;
    int col = order[c];
    __shared__ float rv[256]; __shared__ int ri[256];
    float bv = -1.f; int bidx = N;
    for (int i = t; i < N; i += 256) {
        float av = fabsf(Vm[(size_t)i * N + col]);
        if (av > bv || (av == bv && i < bidx)) { bv = av; bidx = i; }
    }
    rv[t] = bv; ri[t] = bidx;
    __syncthreads();
    for (int off = 128; off; off >>= 1) {
        if (t < off) {
            if (rv[t + off] > rv[t] || (rv[t + off] == rv[t] && ri[t + off] < ri[t])) {
                rv[t] = rv[t + off]; ri[t] = ri[t + off];
            }
        }
        __syncthreads();
    }
    float sv = Vm[(size_t)ri[0] * N + col];
    float s = (sv > 0.f) ? 1.f : ((sv < 0.f) ? -1.f : 0.f);
    double lv = lams[c];
    float f = s * (float)sqrt(lv > 0.0 ? lv : 0.0);
    for (int i = t; i < N; i += 256) out[(size_t)i * NC + c] = Vm[(size_t)i * N + col] * f;
}

extern "C" void kernel_launch(void* const* d_in, const int* in_sizes, int n_in,
                              void* d_out, int out_size, void* d_ws, size_t ws_size,
                              hipStream_t stream) {
    (void)in_sizes; (void)n_in; (void)out_size; (void)ws_size;
    const float* X = (const float*)d_in[0];
    float* out = (float*)d_out;

    double* rm  = (double*)d_ws;                 // N
    double* gm  = rm + N;                        // 1 (+7 pad)
    double* lam = gm + 8;                        // N
    double* lams= lam + N;                       // N
    double* A   = lams + N;                      // N*N fp64
    double* qb  = A + (size_t)N * N;             // 2 * NPAIRS*1024 fp64 (double-buffered)
    float* Dg   = (float*)(qb + 2 * (size_t)NPAIRS * 1024); // N*N f32
    float* Vm   = Dg + (size_t)N * N;            // N*N f32
    float* sq   = Vm + (size_t)N * N;            // N
    int* order  = (int*)(sq + N);                // N
    int* qfl    = order + N;                     // 2 * NPAIRS
    unsigned* flags = (unsigned*)(qfl + 2 * NPAIRS); // 3
    float* dist = (float*)A;                     // alias: dist dies before A is born

    // 1. pairwise distances
    k_rowsq<<<N / 4, 256, 0, stream>>>(X, sq);
    k_dist<<<dim3(32, 32), 256, 0, stream>>>(X, sq, dist);

    // 2. KNN graph
    k_knn<<<N, 256, 0, stream>>>(dist, Dg);
    k_symdiag<<<(N * N) / 256, 256, 0, stream>>>(Dg);

    // 3. blocked Floyd-Warshall
    for (int kb = 0; kb < N / 64; kb++) {
        k_fw12<<<63, 256, 0, stream>>>(Dg, kb);
        k_fw3<<<dim3(32, 32), 256, 0, stream>>>(Dg, kb);
    }

    // 4. double centering -> B (fp64)
    k_rowmean<<<N, 256, 0, stream>>>(Dg, rm);
    k_grand<<<1, 256, 0, stream>>>(rm, gm);
    k_buildB<<<(N * N) / 256, 256, 0, stream>>>(Dg, rm, gm, A);
    k_setV<<<(N * N) / 256, 256, 0, stream>>>(Vm);
    k_initflags<<<1, 1, 0, stream>>>(flags);

    // 5. pipelined two-sided block Jacobi:
    //    local(0) prologue; per round g: trium(g) -> [sweepctl at boundary] ->
    //    fused{ local(g+1) || tri_rest(g) || V(g) }.
    const int G = NSWEEPS * (NB - 1);
    k_local0<<<NPAIRS, 256, 0, stream>>>(A, qb, qfl, flags);
    for (int g = 0; g < G; g++) {
        int round = g % (NB - 1), par = g & 1;
        int nr = (g + 1) % (NB - 1), npar = (g + 1) & 1;
        int nv = (g + 1 < G) ? 1 : 0;
        k_trium<<<NPAIRS, 256, 0, stream>>>(A, qb, qfl, flags, round, par, nr);
        if (((g + 1) % (NB - 1)) == 0)
            k_sweepctl<<<1, 1, 0, stream>>>(flags);
        k_fused<<<NPAIRS + NTRI + NVS, 256, 0, stream>>>(A, Vm, qb, qfl, flags,
                                                         round, par, nr, npar, nv);
    }

    // 6. sort eigenvalues, sign-fix, scale, write output
    k_lambda<<<N / 256, 256, 0, stream>>>(A, lam);
    k_sort<<<1, 1024, 0, stream>>>(lam, lams, order);
    k_out<<<NC, 256, 0, stream>>>(Vm, lams, order, out);
}